// Round 6
// baseline (788.591 us; speedup 1.0000x reference)
//
#include <hip/hip_runtime.h>
#include <hip/hip_bf16.h>
#include <cstdint>
#include <cstddef>

typedef __hip_bfloat16 bf16;
using short8 = __attribute__((ext_vector_type(8))) short;
using f32x4  = __attribute__((ext_vector_type(4))) float;
using float4v = __attribute__((ext_vector_type(4))) float;
using uint4v  = __attribute__((ext_vector_type(4))) unsigned int;

__device__ __forceinline__ float s2f(short s) {
  unsigned u = ((unsigned)(unsigned short)s) << 16;
  return __builtin_bit_cast(float, u);
}
__device__ __forceinline__ short f2s(float f) {  // RNE f32->bf16
  unsigned u = __builtin_bit_cast(unsigned, f);
  u += 0x7fffu + ((u >> 16) & 1u);
  return (short)(u >> 16);
}
__device__ __forceinline__ float bclo(unsigned u) { return __builtin_bit_cast(float, u << 16); }
__device__ __forceinline__ float bchi(unsigned u) { return __builtin_bit_cast(float, u & 0xFFFF0000u); }

// ---------------- merged 1x1 conv + PReLU into zero-padded (+1 ring) f32 outputs ----
__global__ __launch_bounds__(256) void k_conv_all(
    const float* __restrict__ in_l, const float* __restrict__ in_s,
    const float* __restrict__ w_mlb, const float* __restrict__ b_mlb, const float* __restrict__ a_mlb,
    const float* __restrict__ w_m,   const float* __restrict__ b_m,   const float* __restrict__ a_m,
    const float* __restrict__ w_asm, const float* __restrict__ b_asm, const float* __restrict__ a_asm,
    float* __restrict__ MBpad, float* __restrict__ REFpad, float* __restrict__ BASEpad,
    int t1, int t2, int t3)
{
  int idx = blockIdx.x * 256 + threadIdx.x;
  const float *in, *w, *bi, *ap; float* o; int Cout, Hin, Win;
  if (idx < t1) { in = in_l; w = w_mlb; bi = b_mlb; ap = a_mlb; o = MBpad; Cout = 32; Hin = 96; Win = 96; }
  else if (idx < t1 + t2) { idx -= t1; in = in_s; w = w_m; bi = b_m; ap = a_m; o = REFpad; Cout = 32; Hin = 48; Win = 48; }
  else if (idx < t1 + t2 + t3) { idx -= t1 + t2; in = in_s; w = w_asm; bi = b_asm; ap = a_asm; o = BASEpad; Cout = 64; Hin = 48; Win = 48; }
  else return;
  int Wp = Win + 2, Hp = Hin + 2;
  int x = idx % Wp;
  int t = idx / Wp;
  int y = t % Hp; t /= Hp;
  int oc = t % Cout; int n = t / Cout;
  if (x == 0 || x == Wp - 1 || y == 0 || y == Hp - 1) { o[idx] = 0.0f; return; }
  int cs = Hin * Win;
  const float* ip = in + (size_t)n * 64 * cs + (size_t)(y - 1) * Win + (x - 1);
  const float* wp = w + oc * 64;
  float s = bi[oc];
#pragma unroll 16
  for (int ci = 0; ci < 64; ci++)
    s += wp[ci] * ip[(size_t)ci * cs];
  float a = ap[0];
  o[idx] = s >= 0.0f ? s : a * s;
}

// ---------------- merged gather/pack: Kp (stride 320) + Xp (stride 320) + Bb --------
__global__ __launch_bounds__(256) void k_gather_all(
    const float* __restrict__ mbpad, const float* __restrict__ refpad,
    const float* __restrict__ basepad,
    bf16* __restrict__ Kp, bf16* __restrict__ Xp, bf16* __restrict__ Bb)
{
  int b = blockIdx.x;
  int tid = threadIdx.x;
  if (b < 2304) {
    // key patches, L2-normalized, scale 10 folded; one wave per (n,l); stride 320
    int wid = b * 4 + (tid >> 6);
    int lane = tid & 63;
    int n = wid / 2304, l = wid % 2304, lh = l / 48, lw = l % 48;
    float v[5]; float ss = 0.f;
#pragma unroll
    for (int i = 0; i < 5; i++) {
      int k = lane + 64 * i; v[i] = 0.f;
      if (k < 288) {
        int c = k / 9, rr = (k % 9) / 3, sc = k % 3;
        v[i] = refpad[((size_t)(n * 32 + c) * 50 + lh + rr) * 50 + lw + sc];
        ss += v[i] * v[i];
      }
    }
#pragma unroll
    for (int off = 32; off; off >>= 1) ss += __shfl_xor(ss, off);
    float inv = 10.f / (sqrtf(ss) + 1e-4f);
#pragma unroll
    for (int i = 0; i < 5; i++) {
      int k = lane + 64 * i;
      Kp[(size_t)wid * 320 + k] = __float2bfloat16(k < 288 ? v[i] * inv : 0.f);
    }
  } else if (b < 2304 + 46080) {
    // query patches Xp[n][p][320]
    int idx = (b - 2304) * 256 + tid;
    int k = idx % 320; int p = (idx / 320) % 9216; int n = idx / (320 * 9216);
    float val = 0.f;
    if (k < 288) {
      int c = k / 9, rr = (k % 9) / 3, sc = k % 3;
      int ph = p / 96, pw = p % 96;
      val = mbpad[((size_t)(n * 32 + c) * 98 + ph + rr) * 98 + pw + sc];
    }
    Xp[idx] = __float2bfloat16(val);
  } else {
    // base value matrix Bb[n][o][l]
    int idx = (b - 48384) * 256 + tid;
    int l = idx % 2304; int o = (idx / 2304) % 64; int n = idx / (2304 * 64);
    int lh = l / 48, lw = l % 48;
    Bb[idx] = __float2bfloat16(basepad[((size_t)(n * 64 + o) * 50 + lh + 1) * 50 + lw + 1]);
  }
}

// ---------------- stage 1: QK tile GEMM + chunk-local softmax, writes P~ ------------
// block: 64q x 256l, 2x2 waves of 32q x 128l. 64-wide k-stages.
// vmcnt is FIFO: X (A-operand) fragments for the CURRENT stage are loaded FIRST
// (right after barrier B), then the 8 K-prefetch loads for stage s+1 are issued.
// Compute waits for X at vmcnt(8); the K loads stay outstanding until next stage's
// ds_write (a full compute phase of latency cover). X is single-buffered.
__global__ __launch_bounds__(256, 3) void k_qk(
    const bf16* __restrict__ Xp, const bf16* __restrict__ Kp,
    bf16* __restrict__ attnT, float* __restrict__ statsM, float* __restrict__ statsZ,
    int n, int qlo)
{
  __shared__ __align__(16) short KsPs[256 * 72];   // union: Ks 256x(64+8) / Ps 64x264
  __shared__ float Sm[2][2][32];
  __shared__ float Sz[2][2][32];
  int tid = threadIdx.x, lane = tid & 63, wv = tid >> 6;
  int quad = lane >> 4, m16 = lane & 15;
  int wr = wv >> 1, wc = wv & 1;
  int q0 = qlo + blockIdx.x * 64;
  int l0 = blockIdx.y * 256;

  f32x4 acc[2][8];
#pragma unroll
  for (int mi = 0; mi < 2; mi++)
#pragma unroll
    for (int t = 0; t < 8; t++) acc[mi][t] = (f32x4){0.f, 0.f, 0.f, 0.f};

  const short* Xrow = (const short*)Xp + ((size_t)n * 9216 + q0 + wr * 32 + m16) * 320;
  const short* Ksrc = (const short*)Kp + ((size_t)n * 2304 + l0) * 320;
  int srow = tid >> 2;            // 0..63 (rows srow + 64p)
  int scol = (tid & 3) * 16;      // 0,16,32,48

  // prologue: stage-0 K loads only
  short8 pf[8];
#pragma unroll
  for (int p = 0; p < 4; p++)
#pragma unroll
    for (int v = 0; v < 2; v++)
      pf[p * 2 + v] = *(const short8*)&Ksrc[(size_t)(srow + 64 * p) * 320 + scol + v * 8];

#pragma unroll
  for (int s = 0; s < 5; s++) {
    if (s) __syncthreads();       // (A) read->write hazard; drains pf(s) loads,
                                  //     which had all of compute(s-1) in flight
#pragma unroll
    for (int p = 0; p < 4; p++)
#pragma unroll
      for (int v = 0; v < 2; v++)
        *(short8*)&KsPs[(srow + 64 * p) * 72 + scol + v * 8] = pf[p * 2 + v];
    __syncthreads();              // (B) write->read hazard
    short8 xa0 = *(const short8*)&Xrow[s * 64 + quad * 8];
    short8 xa1 = *(const short8*)&Xrow[16 * 320 + s * 64 + quad * 8];
    short8 xa2 = *(const short8*)&Xrow[s * 64 + 32 + quad * 8];
    short8 xa3 = *(const short8*)&Xrow[16 * 320 + s * 64 + 32 + quad * 8];
    if (s < 4) {
      int kn = (s + 1) * 64;
#pragma unroll
      for (int p = 0; p < 4; p++)
#pragma unroll
        for (int v = 0; v < 2; v++)
          pf[p * 2 + v] = *(const short8*)&Ksrc[(size_t)(srow + 64 * p) * 320 + kn + scol + v * 8];
    }
#pragma unroll
    for (int half = 0; half < 2; half++) {
      int kc = s * 64 + half * 32;
      if (kc >= 288) break;       // K=288; skip zero tail
      short8 a0 = half ? xa2 : xa0;
      short8 a1 = half ? xa3 : xa1;
#pragma unroll
      for (int t = 0; t < 8; t++) {
        short8 bfr = *(const short8*)&KsPs[(wc * 128 + t * 16 + m16) * 72 + half * 32 + quad * 8];
        acc[0][t] = __builtin_amdgcn_mfma_f32_16x16x32_bf16(a0, bfr, acc[0][t], 0, 0, 0);
        acc[1][t] = __builtin_amdgcn_mfma_f32_16x16x32_bf16(a1, bfr, acc[1][t], 0, 0, 0);
      }
    }
  }

  // local stats over this wave's 128 l
  float mloc[2][4], zloc[2][4], scale[2][4];
#pragma unroll
  for (int mi = 0; mi < 2; mi++)
#pragma unroll
    for (int r = 0; r < 4; r++) mloc[mi][r] = -3.0e38f;
#pragma unroll
  for (int mi = 0; mi < 2; mi++)
#pragma unroll
    for (int t = 0; t < 8; t++)
#pragma unroll
      for (int r = 0; r < 4; r++) mloc[mi][r] = fmaxf(mloc[mi][r], acc[mi][t][r]);
#pragma unroll
  for (int off = 1; off < 16; off <<= 1)
#pragma unroll
    for (int mi = 0; mi < 2; mi++)
#pragma unroll
      for (int r = 0; r < 4; r++) mloc[mi][r] = fmaxf(mloc[mi][r], __shfl_xor(mloc[mi][r], off));
#pragma unroll
  for (int mi = 0; mi < 2; mi++)
#pragma unroll
    for (int r = 0; r < 4; r++) zloc[mi][r] = 0.f;
#pragma unroll
  for (int mi = 0; mi < 2; mi++)
#pragma unroll
    for (int t = 0; t < 8; t++)
#pragma unroll
      for (int r = 0; r < 4; r++) {
        float e = __expf(acc[mi][t][r] - mloc[mi][r]);
        acc[mi][t][r] = e;
        zloc[mi][r] += e;
      }
#pragma unroll
  for (int off = 1; off < 16; off <<= 1)
#pragma unroll
    for (int mi = 0; mi < 2; mi++)
#pragma unroll
      for (int r = 0; r < 4; r++) zloc[mi][r] += __shfl_xor(zloc[mi][r], off);
  if (m16 == 0) {
#pragma unroll
    for (int mi = 0; mi < 2; mi++)
#pragma unroll
      for (int r = 0; r < 4; r++) {
        int qi = mi * 16 + quad * 4 + r;
        Sm[wc][wr][qi] = mloc[mi][r];
        Sz[wc][wr][qi] = zloc[mi][r];
      }
  }
  __syncthreads();   // stats visible; also guards Ks reuse as Ps below
#pragma unroll
  for (int mi = 0; mi < 2; mi++)
#pragma unroll
    for (int r = 0; r < 4; r++) {
      int qi = mi * 16 + quad * 4 + r;
      float mo = Sm[wc ^ 1][wr][qi];
      float zo = Sz[wc ^ 1][wr][qi];
      float mc = fmaxf(mloc[mi][r], mo);
      float sc = __expf(mloc[mi][r] - mc);
      scale[mi][r] = sc;
      if (m16 == 0 && wc == 0) {
        float zc = zloc[mi][r] * sc + zo * __expf(mo - mc);
        int qq = q0 + wr * 32 + qi;
        statsM[blockIdx.y * 9216 + qq] = mc;
        statsZ[blockIdx.y * 9216 + qq] = zc;
      }
    }
  // write P~ tile through LDS (coalesced global stores)
#pragma unroll
  for (int mi = 0; mi < 2; mi++)
#pragma unroll
    for (int t = 0; t < 8; t++)
#pragma unroll
      for (int r = 0; r < 4; r++)
        KsPs[(wr * 32 + mi * 16 + quad * 4 + r) * 264 + wc * 128 + t * 16 + m16] =
            f2s(acc[mi][t][r] * scale[mi][r]);
  __syncthreads();
  {
    int row = tid >> 2, part = tid & 3;
    short* dst = (short*)attnT + (size_t)(q0 - qlo + row) * 2304 + l0 + part * 64;
    const short* sp = &KsPs[row * 264 + part * 64];
#pragma unroll
    for (int v = 0; v < 8; v++)
      *(short8*)&dst[v * 8] = *(const short8*)&sp[v * 8];
  }
}

// ---------------- stage 2: combine chunk stats -> alpha[c][q] ----------------
__global__ __launch_bounds__(256) void k_alpha(
    const float* __restrict__ statsM, const float* __restrict__ statsZ,
    float* __restrict__ alpha, int qlo, int qlen)
{
  int i = blockIdx.x * 256 + threadIdx.x;
  if (i >= qlen) return;
  int q = qlo + i;
  float M = -3.0e38f;
#pragma unroll
  for (int c = 0; c < 9; c++) M = fmaxf(M, statsM[c * 9216 + q]);
  float Z = 0.f;
#pragma unroll
  for (int c = 0; c < 9; c++) Z += statsZ[c * 9216 + q] * __expf(statsM[c * 9216 + q] - M);
  float invZ = 1.f / Z;
#pragma unroll
  for (int c = 0; c < 9; c++) alpha[c * 9216 + q] = __expf(statsM[c * 9216 + q] - M) * invZ;
}

// ---- 9-point diagonal stencil for one (q, 8-l group): A2[l0..l0+7, q] -------------
// 8-wide variant of the proven stencil16: same per-element arithmetic and
// accumulation order (di: -1,0,+1 outer; dj: 0,-1,+1 inner), 16B-aligned uint4
// loads (l0 is a multiple of 8; 8 | 48 so a group never crosses an lh row).
// Chunk-boundary alpha fixups: elem0 (dj=-1) crosses into chunk c0-1 iff
// (lb&255)==0; elem7 (dj=+1) crosses into chunk c0+1 iff (lb&255)==248.
__device__ __forceinline__ void stencil8(
    const short* __restrict__ att, const float* __restrict__ alpha,
    int q, int l0, int qlo, float* __restrict__ acc)
{
  int h = q / 96, w = q - h * 96;
  int lh = l0 / 48, lw0 = l0 - lh * 48;   // 0,8,16,24,32,40
#pragma unroll
  for (int k = 0; k < 8; k++) acc[k] = 0.f;
#pragma unroll
  for (int di = -1; di <= 1; di++) {
    int hh = h + di, lhh = lh + di;
    if (hh < 0 || hh >= 96 || lhh < 0 || lhh >= 48) continue;
    int lb = l0 + 48 * di;            // multiple of 8 -> 16B aligned
    int qv = q + 96 * di;
    const short* r0 = att + (size_t)(qv - qlo) * 2304;
    int c0 = lb >> 8;                 // 8-span never crosses a 256-chunk
    const float* alc = alpha + c0 * 9216;
    { // dj = 0
      float a = alc[qv];
      uint4v V = *(const uint4v*)(r0 + lb);
#pragma unroll
      for (int k = 0; k < 4; k++) {
        acc[2 * k]     += bclo(V[k]) * a;
        acc[2 * k + 1] += bchi(V[k]) * a;
      }
    }
    if (w > 0) { // dj = -1: shorts [lb-1 .. lb+6]; elem0 may be chunk c0-1
      const short* rm = r0 - 2304;
      int qp = qv - 1;
      float am = alc[qp];
      float a0 = ((lb & 255) == 0 && c0 > 0) ? alpha[(c0 - 1) * 9216 + qp] : am;
      uint4v M = *(const uint4v*)(rm + lb);
      unsigned P = *(const unsigned*)(rm + lb - 2);
      unsigned D[4] = { M[0], M[1], M[2], M[3] };
      unsigned E0 = (P >> 16) | (D[0] << 16);
      if (lw0 == 0) E0 &= 0xFFFF0000u;     // elem0 would wrap to prev lh row
      acc[0] += bclo(E0) * a0;  acc[1] += bchi(E0) * am;
#pragma unroll
      for (int k = 1; k < 4; k++) {
        unsigned Ek = (D[k - 1] >> 16) | (D[k] << 16);
        acc[2 * k] += bclo(Ek) * am;  acc[2 * k + 1] += bchi(Ek) * am;
      }
    }
    if (w < 95) { // dj = +1: shorts [lb+1 .. lb+8]; elem7 may be chunk c0+1
      const short* rp = r0 + 2304;
      int qp = qv + 1;
      float am = alc[qp];
      float a7 = ((lb & 255) == 248 && c0 < 8) ? alpha[(c0 + 1) * 9216 + qp] : am;
      uint4v Pp = *(const uint4v*)(rp + lb);
      unsigned N = *(const unsigned*)(rp + lb + 8);
      unsigned D[5] = { Pp[0], Pp[1], Pp[2], Pp[3], N };
#pragma unroll
      for (int k = 0; k < 3; k++) {
        unsigned Fk = (D[k] >> 16) | (D[k + 1] << 16);
        acc[2 * k] += bclo(Fk) * am;  acc[2 * k + 1] += bchi(Fk) * am;
      }
      unsigned F3 = (D[3] >> 16) | (D[4] << 16);
      if (lw0 == 40) F3 &= 0x0000FFFFu;    // elem7 would wrap to next lh row
      acc[6] += bclo(F3) * am;  acc[7] += bchi(F3) * a7;
    }
  }
}

// ---- fused stencil + PV GEMM, barrier-free main loop ------------------------------
// block = 16q x 64o, 4 waves each own 576 of K=2304. Each lane computes the stencil
// for EXACTLY the A-fragment it feeds to MFMA: lane (m16=q-row, quad) owns
// l = kw + ks*32 + quad*8 .. +7 for ks in {0,1}. No LDS A-tile, no cross-lane
// traffic, no barriers in the main loop (rounds 3-5 lesson: cross-lane LDS without
// block-wide fences is either wrong or slow). Compiler pipelines stencil loads,
// B loads and MFMAs freely across the 9 chunks. Same f2s rounding + per-wave
// K-partition as the k_a2 -> k_pv3 pair -> bit-identical results.
// XCD swizzle: blocks b, b±6 share attnT rows (di taps); chunked mapping puts them
// on the same XCD so the 3x attnT re-fetch collapses in L2. gridDim.x % 8 == 0 for
// all psplit choices (576/288/144).
__global__ __launch_bounds__(256) void k_a2pv(
    const bf16* __restrict__ attnT, const float* __restrict__ alpha,
    const bf16* __restrict__ Bb, const float* __restrict__ inl,
    float* __restrict__ out, int n, int q0base, int qlo)
{
  __shared__ float Cred[4][16][67];
  int bpx = gridDim.x >> 3;
  int nb = (blockIdx.x & 7) * bpx + (blockIdx.x >> 3);
  int tid = threadIdx.x, lane = tid & 63, wv = tid >> 6;
  int quad = lane >> 4, m16 = lane & 15;
  int qb = nb * 16;
  int kbase = wv * 576;
  int qabs = q0base + qb + m16;
  const short* att = (const short*)attnT;
  const short* Bp = (const short*)Bb + (size_t)n * 64 * 2304;
  f32x4 acc[4];
#pragma unroll
  for (int t = 0; t < 4; t++) acc[t] = (f32x4){0.f, 0.f, 0.f, 0.f};

#pragma unroll
  for (int ch = 0; ch < 9; ch++) {
    int kw = kbase + ch * 64;
    // B fragments for this chunk (independent of the stencil; issued first)
    short8 bfr[2][4];
#pragma unroll
    for (int ks = 0; ks < 2; ks++)
#pragma unroll
      for (int ni = 0; ni < 4; ni++)
        bfr[ks][ni] = *(const short8*)&Bp[(size_t)(ni * 16 + m16) * 2304 + kw + ks * 32 + quad * 8];
#pragma unroll
    for (int ks = 0; ks < 2; ks++) {
      float sac[8];
      stencil8(att, alpha, qabs, kw + ks * 32 + quad * 8, qlo, sac);
      short8 a;
#pragma unroll
      for (int k = 0; k < 8; k++) a[k] = f2s(sac[k]);
#pragma unroll
      for (int ni = 0; ni < 4; ni++)
        acc[ni] = __builtin_amdgcn_mfma_f32_16x16x32_bf16(a, bfr[ks][ni], acc[ni], 0, 0, 0);
    }
  }

#pragma unroll
  for (int ni = 0; ni < 4; ni++)
#pragma unroll
    for (int r = 0; r < 4; r++)
      Cred[wv][quad * 4 + r][ni * 16 + m16] = acc[ni][r];
  __syncthreads();
  {
    int o = tid >> 2;                // 0..63
    int qg = (tid & 3) * 4;          // 0..12
    float4v s;
#pragma unroll
    for (int j = 0; j < 4; j++)
      s[j] = Cred[0][qg + j][o] + Cred[1][qg + j][o] + Cred[2][qg + j][o] + Cred[3][qg + j][o];
    size_t oid = ((size_t)(n * 64 + o)) * 9216 + q0base + qb + qg;
    float4v r4 = *(const float4v*)&inl[oid];
    float4v y;
#pragma unroll
    for (int j = 0; j < 4; j++) y[j] = 0.25f * s[j] + r4[j];
    *(float4v*)&out[oid] = y;
  }
}

extern "C" void kernel_launch(void* const* d_in, const int* in_sizes, int n_in,
                              void* d_out, int out_size, void* d_ws, size_t ws_size,
                              hipStream_t stream)
{
  (void)in_sizes; (void)n_in; (void)out_size;
  const float* input_l = (const float*)d_in[0];
  const float* input_s = (const float*)d_in[1];
  const float* w_mlb = (const float*)d_in[2];
  const float* b_mlb = (const float*)d_in[3];
  const float* a_mlb = (const float*)d_in[4];
  const float* w_m   = (const float*)d_in[5];
  const float* b_m   = (const float*)d_in[6];
  const float* a_m   = (const float*)d_in[7];
  const float* w_asm = (const float*)d_in[8];
  const float* b_asm = (const float*)d_in[9];
  const float* a_asm = (const float*)d_in[10];
  float* out = (float*)d_out;

  char* base = (char*)d_ws;
  size_t off = 0;
  auto carve = [&](size_t bytes) -> char* {
    char* r = base + off;
    off += (bytes + 255) & ~(size_t)255;
    return r;
  };

  float* MBpad   = (float*)carve((size_t)4 * 32 * 98 * 98 * 4);
  float* REFpad  = (float*)carve((size_t)4 * 32 * 50 * 50 * 4);
  float* BASEpad = (float*)carve((size_t)4 * 64 * 50 * 50 * 4);
  bf16*  Kp      = (bf16*)carve((size_t)4 * 2304 * 320 * 2);
  bf16*  Xp      = (bf16*)carve((size_t)4 * 9216 * 320 * 2);
  bf16*  Bb      = (bf16*)carve((size_t)4 * 64 * 2304 * 2);
  float* statsM  = (float*)carve((size_t)9 * 9216 * 4);
  float* statsZ  = (float*)carve((size_t)9 * 9216 * 4);
  float* alpha   = (float*)carve((size_t)9 * 9216 * 4);
  size_t fixedOff = off;

  auto need = [&](int qmax) -> size_t {
    size_t a = ((size_t)qmax * 2304 * 2 + 255) & ~(size_t)255;
    return fixedOff + a;
  };
  int nsplit, qmax, psplit;
  if (need(9216) <= ws_size)      { nsplit = 1; qmax = 9216; psplit = 9216; }
  else if (need(5120) <= ws_size) { nsplit = 2; qmax = 5120; psplit = 4608; }
  else                            { nsplit = 4; qmax = 2816; psplit = 2304; }

  bf16* attnT = (bf16*)carve((size_t)qmax * 2304 * 2);

  // ---- prep (all samples, 2 dispatches) ----
  {
    int t1 = 4 * 32 * 98 * 98;
    int t2 = 4 * 32 * 50 * 50;
    int t3 = 4 * 64 * 50 * 50;
    int tt = t1 + t2 + t3;
    k_conv_all<<<dim3((tt + 255) / 256), dim3(256), 0, stream>>>(
        input_l, input_s, w_mlb, b_mlb, a_mlb, w_m, b_m, a_m, w_asm, b_asm, a_asm,
        MBpad, REFpad, BASEpad, t1, t2, t3);
    k_gather_all<<<dim3(2304 + 46080 + 2304), dim3(256), 0, stream>>>(
        MBpad, REFpad, BASEpad, Kp, Xp, Bb);
  }

  // ---- attention per (sample, query band) ----
  for (int n = 0; n < 4; n++) {
    for (int s = 0; s < nsplit; s++) {
      int q0 = s * psplit;
      int qlo = q0 - 256; if (qlo < 0) qlo = 0;
      int qhi = q0 + psplit + 256; if (qhi > 9216) qhi = 9216;
      int qlen = qhi - qlo;  // multiple of 256 by construction
      k_qk<<<dim3(qlen / 64, 9), dim3(256), 0, stream>>>(Xp, Kp, attnT, statsM, statsZ, n, qlo);
      k_alpha<<<dim3(qlen / 256), dim3(256), 0, stream>>>(statsM, statsZ, alpha, qlo, qlen);
      k_a2pv<<<dim3(psplit / 16), dim3(256), 0, stream>>>(attnT, alpha, Bb, input_l, out, n, q0, qlo);
    }
  }
}

// Round 7
// 755.705 us; speedup vs baseline: 1.0435x; 1.0435x over previous
//
#include <hip/hip_runtime.h>
#include <hip/hip_bf16.h>
#include <cstdint>
#include <cstddef>

typedef __hip_bfloat16 bf16;
using short8 = __attribute__((ext_vector_type(8))) short;
using f32x4  = __attribute__((ext_vector_type(4))) float;
using float4v = __attribute__((ext_vector_type(4))) float;
using uint4v  = __attribute__((ext_vector_type(4))) unsigned int;

__device__ __forceinline__ float s2f(short s) {
  unsigned u = ((unsigned)(unsigned short)s) << 16;
  return __builtin_bit_cast(float, u);
}
__device__ __forceinline__ short f2s(float f) {  // RNE f32->bf16
  unsigned u = __builtin_bit_cast(unsigned, f);
  u += 0x7fffu + ((u >> 16) & 1u);
  return (short)(u >> 16);
}
__device__ __forceinline__ float bclo(unsigned u) { return __builtin_bit_cast(float, u << 16); }
__device__ __forceinline__ float bchi(unsigned u) { return __builtin_bit_cast(float, u & 0xFFFF0000u); }

// ---------------- merged 1x1 conv + PReLU into zero-padded (+1 ring) f32 outputs ----
__global__ __launch_bounds__(256) void k_conv_all(
    const float* __restrict__ in_l, const float* __restrict__ in_s,
    const float* __restrict__ w_mlb, const float* __restrict__ b_mlb, const float* __restrict__ a_mlb,
    const float* __restrict__ w_m,   const float* __restrict__ b_m,   const float* __restrict__ a_m,
    const float* __restrict__ w_asm, const float* __restrict__ b_asm, const float* __restrict__ a_asm,
    float* __restrict__ MBpad, float* __restrict__ REFpad, float* __restrict__ BASEpad,
    int t1, int t2, int t3)
{
  int idx = blockIdx.x * 256 + threadIdx.x;
  const float *in, *w, *bi, *ap; float* o; int Cout, Hin, Win;
  if (idx < t1) { in = in_l; w = w_mlb; bi = b_mlb; ap = a_mlb; o = MBpad; Cout = 32; Hin = 96; Win = 96; }
  else if (idx < t1 + t2) { idx -= t1; in = in_s; w = w_m; bi = b_m; ap = a_m; o = REFpad; Cout = 32; Hin = 48; Win = 48; }
  else if (idx < t1 + t2 + t3) { idx -= t1 + t2; in = in_s; w = w_asm; bi = b_asm; ap = a_asm; o = BASEpad; Cout = 64; Hin = 48; Win = 48; }
  else return;
  int Wp = Win + 2, Hp = Hin + 2;
  int x = idx % Wp;
  int t = idx / Wp;
  int y = t % Hp; t /= Hp;
  int oc = t % Cout; int n = t / Cout;
  if (x == 0 || x == Wp - 1 || y == 0 || y == Hp - 1) { o[idx] = 0.0f; return; }
  int cs = Hin * Win;
  const float* ip = in + (size_t)n * 64 * cs + (size_t)(y - 1) * Win + (x - 1);
  const float* wp = w + oc * 64;
  float s = bi[oc];
#pragma unroll 16
  for (int ci = 0; ci < 64; ci++)
    s += wp[ci] * ip[(size_t)ci * cs];
  float a = ap[0];
  o[idx] = s >= 0.0f ? s : a * s;
}

// ---------------- residual pre-fill: out = input_l (PV partials atomicAdd on top) --
__global__ __launch_bounds__(256) void k_resid(
    const float* __restrict__ inl, float* __restrict__ out, int total4)
{
  int i = blockIdx.x * 256 + threadIdx.x;
  if (i < total4)
    ((float4v*)out)[i] = ((const float4v*)inl)[i];
}

// ---------------- merged gather/pack: Kp (stride 320) + Xp (stride 320) + Bb --------
__global__ __launch_bounds__(256) void k_gather_all(
    const float* __restrict__ mbpad, const float* __restrict__ refpad,
    const float* __restrict__ basepad,
    bf16* __restrict__ Kp, bf16* __restrict__ Xp, bf16* __restrict__ Bb)
{
  int b = blockIdx.x;
  int tid = threadIdx.x;
  if (b < 2304) {
    // key patches, L2-normalized, scale 10 folded; one wave per (n,l); stride 320
    int wid = b * 4 + (tid >> 6);
    int lane = tid & 63;
    int n = wid / 2304, l = wid % 2304, lh = l / 48, lw = l % 48;
    float v[5]; float ss = 0.f;
#pragma unroll
    for (int i = 0; i < 5; i++) {
      int k = lane + 64 * i; v[i] = 0.f;
      if (k < 288) {
        int c = k / 9, rr = (k % 9) / 3, sc = k % 3;
        v[i] = refpad[((size_t)(n * 32 + c) * 50 + lh + rr) * 50 + lw + sc];
        ss += v[i] * v[i];
      }
    }
#pragma unroll
    for (int off = 32; off; off >>= 1) ss += __shfl_xor(ss, off);
    float inv = 10.f / (sqrtf(ss) + 1e-4f);
#pragma unroll
    for (int i = 0; i < 5; i++) {
      int k = lane + 64 * i;
      Kp[(size_t)wid * 320 + k] = __float2bfloat16(k < 288 ? v[i] * inv : 0.f);
    }
  } else if (b < 2304 + 46080) {
    // query patches Xp[n][p][320]
    int idx = (b - 2304) * 256 + tid;
    int k = idx % 320; int p = (idx / 320) % 9216; int n = idx / (320 * 9216);
    float val = 0.f;
    if (k < 288) {
      int c = k / 9, rr = (k % 9) / 3, sc = k % 3;
      int ph = p / 96, pw = p % 96;
      val = mbpad[((size_t)(n * 32 + c) * 98 + ph + rr) * 98 + pw + sc];
    }
    Xp[idx] = __float2bfloat16(val);
  } else {
    // base value matrix Bb[n][o][l]
    int idx = (b - 48384) * 256 + tid;
    int l = idx % 2304; int o = (idx / 2304) % 64; int n = idx / (2304 * 64);
    int lh = l / 48, lw = l % 48;
    Bb[idx] = __float2bfloat16(basepad[((size_t)(n * 64 + o) * 50 + lh + 1) * 50 + lw + 1]);
  }
}

// ---------------- stage 1: QK tile GEMM + chunk-local softmax, writes P~ ------------
// block: 64q x 256l, 2x2 waves of 32q x 128l. 64-wide k-stages.
// vmcnt is FIFO: X (A-operand) fragments for the CURRENT stage are loaded FIRST
// (right after barrier B), then the 8 K-prefetch loads for stage s+1 are issued.
// Compute waits for X at vmcnt(8); the K loads stay outstanding until next stage's
// ds_write (a full compute phase of latency cover). X is single-buffered.
__global__ __launch_bounds__(256, 3) void k_qk(
    const bf16* __restrict__ Xp, const bf16* __restrict__ Kp,
    bf16* __restrict__ attnT, float* __restrict__ statsM, float* __restrict__ statsZ,
    int n, int qlo)
{
  __shared__ __align__(16) short KsPs[256 * 72];   // union: Ks 256x(64+8) / Ps 64x264
  __shared__ float Sm[2][2][32];
  __shared__ float Sz[2][2][32];
  int tid = threadIdx.x, lane = tid & 63, wv = tid >> 6;
  int quad = lane >> 4, m16 = lane & 15;
  int wr = wv >> 1, wc = wv & 1;
  int q0 = qlo + blockIdx.x * 64;
  int l0 = blockIdx.y * 256;

  f32x4 acc[2][8];
#pragma unroll
  for (int mi = 0; mi < 2; mi++)
#pragma unroll
    for (int t = 0; t < 8; t++) acc[mi][t] = (f32x4){0.f, 0.f, 0.f, 0.f};

  const short* Xrow = (const short*)Xp + ((size_t)n * 9216 + q0 + wr * 32 + m16) * 320;
  const short* Ksrc = (const short*)Kp + ((size_t)n * 2304 + l0) * 320;
  int srow = tid >> 2;            // 0..63 (rows srow + 64p)
  int scol = (tid & 3) * 16;      // 0,16,32,48

  // prologue: stage-0 K loads only
  short8 pf[8];
#pragma unroll
  for (int p = 0; p < 4; p++)
#pragma unroll
    for (int v = 0; v < 2; v++)
      pf[p * 2 + v] = *(const short8*)&Ksrc[(size_t)(srow + 64 * p) * 320 + scol + v * 8];

#pragma unroll
  for (int s = 0; s < 5; s++) {
    if (s) __syncthreads();       // (A) read->write hazard; drains pf(s) loads,
                                  //     which had all of compute(s-1) in flight
#pragma unroll
    for (int p = 0; p < 4; p++)
#pragma unroll
      for (int v = 0; v < 2; v++)
        *(short8*)&KsPs[(srow + 64 * p) * 72 + scol + v * 8] = pf[p * 2 + v];
    __syncthreads();              // (B) write->read hazard
    short8 xa0 = *(const short8*)&Xrow[s * 64 + quad * 8];
    short8 xa1 = *(const short8*)&Xrow[16 * 320 + s * 64 + quad * 8];
    short8 xa2 = *(const short8*)&Xrow[s * 64 + 32 + quad * 8];
    short8 xa3 = *(const short8*)&Xrow[16 * 320 + s * 64 + 32 + quad * 8];
    if (s < 4) {
      int kn = (s + 1) * 64;
#pragma unroll
      for (int p = 0; p < 4; p++)
#pragma unroll
        for (int v = 0; v < 2; v++)
          pf[p * 2 + v] = *(const short8*)&Ksrc[(size_t)(srow + 64 * p) * 320 + kn + scol + v * 8];
    }
#pragma unroll
    for (int half = 0; half < 2; half++) {
      int kc = s * 64 + half * 32;
      if (kc >= 288) break;       // K=288; skip zero tail
      short8 a0 = half ? xa2 : xa0;
      short8 a1 = half ? xa3 : xa1;
#pragma unroll
      for (int t = 0; t < 8; t++) {
        short8 bfr = *(const short8*)&KsPs[(wc * 128 + t * 16 + m16) * 72 + half * 32 + quad * 8];
        acc[0][t] = __builtin_amdgcn_mfma_f32_16x16x32_bf16(a0, bfr, acc[0][t], 0, 0, 0);
        acc[1][t] = __builtin_amdgcn_mfma_f32_16x16x32_bf16(a1, bfr, acc[1][t], 0, 0, 0);
      }
    }
  }

  // local stats over this wave's 128 l
  float mloc[2][4], zloc[2][4], scale[2][4];
#pragma unroll
  for (int mi = 0; mi < 2; mi++)
#pragma unroll
    for (int r = 0; r < 4; r++) mloc[mi][r] = -3.0e38f;
#pragma unroll
  for (int mi = 0; mi < 2; mi++)
#pragma unroll
    for (int t = 0; t < 8; t++)
#pragma unroll
      for (int r = 0; r < 4; r++) mloc[mi][r] = fmaxf(mloc[mi][r], acc[mi][t][r]);
#pragma unroll
  for (int off = 1; off < 16; off <<= 1)
#pragma unroll
    for (int mi = 0; mi < 2; mi++)
#pragma unroll
      for (int r = 0; r < 4; r++) mloc[mi][r] = fmaxf(mloc[mi][r], __shfl_xor(mloc[mi][r], off));
#pragma unroll
  for (int mi = 0; mi < 2; mi++)
#pragma unroll
    for (int r = 0; r < 4; r++) zloc[mi][r] = 0.f;
#pragma unroll
  for (int mi = 0; mi < 2; mi++)
#pragma unroll
    for (int t = 0; t < 8; t++)
#pragma unroll
      for (int r = 0; r < 4; r++) {
        float e = __expf(acc[mi][t][r] - mloc[mi][r]);
        acc[mi][t][r] = e;
        zloc[mi][r] += e;
      }
#pragma unroll
  for (int off = 1; off < 16; off <<= 1)
#pragma unroll
    for (int mi = 0; mi < 2; mi++)
#pragma unroll
      for (int r = 0; r < 4; r++) zloc[mi][r] += __shfl_xor(zloc[mi][r], off);
  if (m16 == 0) {
#pragma unroll
    for (int mi = 0; mi < 2; mi++)
#pragma unroll
      for (int r = 0; r < 4; r++) {
        int qi = mi * 16 + quad * 4 + r;
        Sm[wc][wr][qi] = mloc[mi][r];
        Sz[wc][wr][qi] = zloc[mi][r];
      }
  }
  __syncthreads();   // stats visible; also guards Ks reuse as Ps below
#pragma unroll
  for (int mi = 0; mi < 2; mi++)
#pragma unroll
    for (int r = 0; r < 4; r++) {
      int qi = mi * 16 + quad * 4 + r;
      float mo = Sm[wc ^ 1][wr][qi];
      float zo = Sz[wc ^ 1][wr][qi];
      float mc = fmaxf(mloc[mi][r], mo);
      float sc = __expf(mloc[mi][r] - mc);
      scale[mi][r] = sc;
      if (m16 == 0 && wc == 0) {
        float zc = zloc[mi][r] * sc + zo * __expf(mo - mc);
        int qq = q0 + wr * 32 + qi;
        statsM[blockIdx.y * 9216 + qq] = mc;
        statsZ[blockIdx.y * 9216 + qq] = zc;
      }
    }
  // write P~ tile through LDS (coalesced global stores)
#pragma unroll
  for (int mi = 0; mi < 2; mi++)
#pragma unroll
    for (int t = 0; t < 8; t++)
#pragma unroll
      for (int r = 0; r < 4; r++)
        KsPs[(wr * 32 + mi * 16 + quad * 4 + r) * 264 + wc * 128 + t * 16 + m16] =
            f2s(acc[mi][t][r] * scale[mi][r]);
  __syncthreads();
  {
    int row = tid >> 2, part = tid & 3;
    short* dst = (short*)attnT + (size_t)(q0 - qlo + row) * 2304 + l0 + part * 64;
    const short* sp = &KsPs[row * 264 + part * 64];
#pragma unroll
    for (int v = 0; v < 8; v++)
      *(short8*)&dst[v * 8] = *(const short8*)&sp[v * 8];
  }
}

// ---------------- stage 2: combine chunk stats -> alpha[c][q] ----------------
__global__ __launch_bounds__(256) void k_alpha(
    const float* __restrict__ statsM, const float* __restrict__ statsZ,
    float* __restrict__ alpha, int qlo, int qlen)
{
  int i = blockIdx.x * 256 + threadIdx.x;
  if (i >= qlen) return;
  int q = qlo + i;
  float M = -3.0e38f;
#pragma unroll
  for (int c = 0; c < 9; c++) M = fmaxf(M, statsM[c * 9216 + q]);
  float Z = 0.f;
#pragma unroll
  for (int c = 0; c < 9; c++) Z += statsZ[c * 9216 + q] * __expf(statsM[c * 9216 + q] - M);
  float invZ = 1.f / Z;
#pragma unroll
  for (int c = 0; c < 9; c++) alpha[c * 9216 + q] = __expf(statsM[c * 9216 + q] - M) * invZ;
}

// ---- 9-point diagonal stencil for one (q, 8-l group): A2[l0..l0+7, q] -------------
// 8-wide variant of the proven stencil16: same per-element arithmetic and
// accumulation order (di: -1,0,+1 outer; dj: 0,-1,+1 inner), 16B-aligned uint4
// loads (l0 is a multiple of 8; 8 | 48 so a group never crosses an lh row).
// Chunk-boundary alpha fixups: elem0 (dj=-1) crosses into chunk c0-1 iff
// (lb&255)==0; elem7 (dj=+1) crosses into chunk c0+1 iff (lb&255)==248.
__device__ __forceinline__ void stencil8(
    const short* __restrict__ att, const float* __restrict__ alpha,
    int q, int l0, int qlo, float* __restrict__ acc)
{
  int h = q / 96, w = q - h * 96;
  int lh = l0 / 48, lw0 = l0 - lh * 48;   // 0,8,16,24,32,40
#pragma unroll
  for (int k = 0; k < 8; k++) acc[k] = 0.f;
#pragma unroll
  for (int di = -1; di <= 1; di++) {
    int hh = h + di, lhh = lh + di;
    if (hh < 0 || hh >= 96 || lhh < 0 || lhh >= 48) continue;
    int lb = l0 + 48 * di;            // multiple of 8 -> 16B aligned
    int qv = q + 96 * di;
    const short* r0 = att + (size_t)(qv - qlo) * 2304;
    int c0 = lb >> 8;                 // 8-span never crosses a 256-chunk
    const float* alc = alpha + c0 * 9216;
    { // dj = 0
      float a = alc[qv];
      uint4v V = *(const uint4v*)(r0 + lb);
#pragma unroll
      for (int k = 0; k < 4; k++) {
        acc[2 * k]     += bclo(V[k]) * a;
        acc[2 * k + 1] += bchi(V[k]) * a;
      }
    }
    if (w > 0) { // dj = -1: shorts [lb-1 .. lb+6]; elem0 may be chunk c0-1
      const short* rm = r0 - 2304;
      int qp = qv - 1;
      float am = alc[qp];
      float a0 = ((lb & 255) == 0 && c0 > 0) ? alpha[(c0 - 1) * 9216 + qp] : am;
      uint4v M = *(const uint4v*)(rm + lb);
      unsigned P = *(const unsigned*)(rm + lb - 2);
      unsigned D[4] = { M[0], M[1], M[2], M[3] };
      unsigned E0 = (P >> 16) | (D[0] << 16);
      if (lw0 == 0) E0 &= 0xFFFF0000u;     // elem0 would wrap to prev lh row
      acc[0] += bclo(E0) * a0;  acc[1] += bchi(E0) * am;
#pragma unroll
      for (int k = 1; k < 4; k++) {
        unsigned Ek = (D[k - 1] >> 16) | (D[k] << 16);
        acc[2 * k] += bclo(Ek) * am;  acc[2 * k + 1] += bchi(Ek) * am;
      }
    }
    if (w < 95) { // dj = +1: shorts [lb+1 .. lb+8]; elem7 may be chunk c0+1
      const short* rp = r0 + 2304;
      int qp = qv + 1;
      float am = alc[qp];
      float a7 = ((lb & 255) == 248 && c0 < 8) ? alpha[(c0 + 1) * 9216 + qp] : am;
      uint4v Pp = *(const uint4v*)(rp + lb);
      unsigned N = *(const unsigned*)(rp + lb + 8);
      unsigned D[5] = { Pp[0], Pp[1], Pp[2], Pp[3], N };
#pragma unroll
      for (int k = 0; k < 3; k++) {
        unsigned Fk = (D[k] >> 16) | (D[k + 1] << 16);
        acc[2 * k] += bclo(Fk) * am;  acc[2 * k + 1] += bchi(Fk) * am;
      }
      unsigned F3 = (D[3] >> 16) | (D[4] << 16);
      if (lw0 == 40) F3 &= 0x0000FFFFu;    // elem7 would wrap to next lh row
      acc[6] += bclo(F3) * am;  acc[7] += bchi(F3) * a7;
    }
  }
}

// ---- fused stencil + PV GEMM, barrier-free main loop, split-K x3 across blocks ----
// Round-6 diagnosis: 576 blocks = 9 waves/CU -> stencil load latency exposed (all
// utils <15%). Fix: blockIdx.y = kspl in {0,1,2}; each block's 4 waves own 3 chunks
// each (12 of 36 per block) -> 1728 blocks ~= 27 waves/CU. Each lane still computes
// the stencil for exactly its own MFMA A-fragment (no LDS A-tile, no cross-lane
// traffic, no main-loop barriers). Partials combine via atomicAdd(out, 0.25*s);
// out is pre-filled with the residual (k_resid) in stream order -> idempotent
// across graph replays. f32 ordering changes only across the 3 partials (~ulp).
__global__ __launch_bounds__(256) void k_a2pv(
    const bf16* __restrict__ attnT, const float* __restrict__ alpha,
    const bf16* __restrict__ Bb, float* __restrict__ out,
    int n, int q0base, int qlo)
{
  __shared__ float Cred[4][16][67];
  int bpx = gridDim.x >> 3;
  int nb = (blockIdx.x & 7) * bpx + (blockIdx.x >> 3);   // XCD-chunked q mapping
  int kspl = blockIdx.y;
  int tid = threadIdx.x, lane = tid & 63, wv = tid >> 6;
  int quad = lane >> 4, m16 = lane & 15;
  int qb = nb * 16;
  int kbase = (kspl * 4 + wv) * 192;   // 12 wave-segments x 3 chunks of 64
  int qabs = q0base + qb + m16;
  const short* att = (const short*)attnT;
  const short* Bp = (const short*)Bb + (size_t)n * 64 * 2304;
  f32x4 acc[4];
#pragma unroll
  for (int t = 0; t < 4; t++) acc[t] = (f32x4){0.f, 0.f, 0.f, 0.f};

#pragma unroll
  for (int ch = 0; ch < 3; ch++) {
    int kw = kbase + ch * 64;
    // B fragments for this chunk (independent of the stencil; issued first)
    short8 bfr[2][4];
#pragma unroll
    for (int ks = 0; ks < 2; ks++)
#pragma unroll
      for (int ni = 0; ni < 4; ni++)
        bfr[ks][ni] = *(const short8*)&Bp[(size_t)(ni * 16 + m16) * 2304 + kw + ks * 32 + quad * 8];
#pragma unroll
    for (int ks = 0; ks < 2; ks++) {
      float sac[8];
      stencil8(att, alpha, qabs, kw + ks * 32 + quad * 8, qlo, sac);
      short8 a;
#pragma unroll
      for (int k = 0; k < 8; k++) a[k] = f2s(sac[k]);
#pragma unroll
      for (int ni = 0; ni < 4; ni++)
        acc[ni] = __builtin_amdgcn_mfma_f32_16x16x32_bf16(a, bfr[ks][ni], acc[ni], 0, 0, 0);
    }
  }

#pragma unroll
  for (int ni = 0; ni < 4; ni++)
#pragma unroll
    for (int r = 0; r < 4; r++)
      Cred[wv][quad * 4 + r][ni * 16 + m16] = acc[ni][r];
  __syncthreads();
  {
    int o = tid >> 2;                // 0..63
    int qg = (tid & 3) * 4;          // 0..12
    size_t oid = ((size_t)(n * 64 + o)) * 9216 + q0base + qb + qg;
#pragma unroll
    for (int j = 0; j < 4; j++) {
      float s = Cred[0][qg + j][o] + Cred[1][qg + j][o] + Cred[2][qg + j][o] + Cred[3][qg + j][o];
      atomicAdd(&out[oid + j], 0.25f * s);
    }
  }
}

extern "C" void kernel_launch(void* const* d_in, const int* in_sizes, int n_in,
                              void* d_out, int out_size, void* d_ws, size_t ws_size,
                              hipStream_t stream)
{
  (void)in_sizes; (void)n_in; (void)out_size;
  const float* input_l = (const float*)d_in[0];
  const float* input_s = (const float*)d_in[1];
  const float* w_mlb = (const float*)d_in[2];
  const float* b_mlb = (const float*)d_in[3];
  const float* a_mlb = (const float*)d_in[4];
  const float* w_m   = (const float*)d_in[5];
  const float* b_m   = (const float*)d_in[6];
  const float* a_m   = (const float*)d_in[7];
  const float* w_asm = (const float*)d_in[8];
  const float* b_asm = (const float*)d_in[9];
  const float* a_asm = (const float*)d_in[10];
  float* out = (float*)d_out;

  char* base = (char*)d_ws;
  size_t off = 0;
  auto carve = [&](size_t bytes) -> char* {
    char* r = base + off;
    off += (bytes + 255) & ~(size_t)255;
    return r;
  };

  float* MBpad   = (float*)carve((size_t)4 * 32 * 98 * 98 * 4);
  float* REFpad  = (float*)carve((size_t)4 * 32 * 50 * 50 * 4);
  float* BASEpad = (float*)carve((size_t)4 * 64 * 50 * 50 * 4);
  bf16*  Kp      = (bf16*)carve((size_t)4 * 2304 * 320 * 2);
  bf16*  Xp      = (bf16*)carve((size_t)4 * 9216 * 320 * 2);
  bf16*  Bb      = (bf16*)carve((size_t)4 * 64 * 2304 * 2);
  float* statsM  = (float*)carve((size_t)9 * 9216 * 4);
  float* statsZ  = (float*)carve((size_t)9 * 9216 * 4);
  float* alpha   = (float*)carve((size_t)9 * 9216 * 4);
  size_t fixedOff = off;

  auto need = [&](int qmax) -> size_t {
    size_t a = ((size_t)qmax * 2304 * 2 + 255) & ~(size_t)255;
    return fixedOff + a;
  };
  int nsplit, qmax, psplit;
  if (need(9216) <= ws_size)      { nsplit = 1; qmax = 9216; psplit = 9216; }
  else if (need(5120) <= ws_size) { nsplit = 2; qmax = 5120; psplit = 4608; }
  else                            { nsplit = 4; qmax = 2816; psplit = 2304; }

  bf16* attnT = (bf16*)carve((size_t)qmax * 2304 * 2);

  // ---- prep (all samples, 3 dispatches) ----
  {
    int t1 = 4 * 32 * 98 * 98;
    int t2 = 4 * 32 * 50 * 50;
    int t3 = 4 * 64 * 50 * 50;
    int tt = t1 + t2 + t3;
    k_conv_all<<<dim3((tt + 255) / 256), dim3(256), 0, stream>>>(
        input_l, input_s, w_mlb, b_mlb, a_mlb, w_m, b_m, a_m, w_asm, b_asm, a_asm,
        MBpad, REFpad, BASEpad, t1, t2, t3);
    k_resid<<<dim3(2304), dim3(256), 0, stream>>>(input_l, out, 4 * 64 * 9216 / 4);
    k_gather_all<<<dim3(2304 + 46080 + 2304), dim3(256), 0, stream>>>(
        MBpad, REFpad, BASEpad, Kp, Xp, Bb);
  }

  // ---- attention per (sample, query band) ----
  for (int n = 0; n < 4; n++) {
    for (int s = 0; s < nsplit; s++) {
      int q0 = s * psplit;
      int qlo = q0 - 256; if (qlo < 0) qlo = 0;
      int qhi = q0 + psplit + 256; if (qhi > 9216) qhi = 9216;
      int qlen = qhi - qlo;  // multiple of 256 by construction
      k_qk<<<dim3(qlen / 64, 9), dim3(256), 0, stream>>>(Xp, Kp, attnT, statsM, statsZ, n, qlo);
      k_alpha<<<dim3(qlen / 256), dim3(256), 0, stream>>>(statsM, statsZ, alpha, qlo, qlen);
      k_a2pv<<<dim3(psplit / 16, 3), dim3(256), 0, stream>>>(attnT, alpha, Bb, out, n, q0, qlo);
    }
  }
}

// Round 8
// 583.796 us; speedup vs baseline: 1.3508x; 1.2945x over previous
//
#include <hip/hip_runtime.h>
#include <hip/hip_bf16.h>
#include <cstdint>
#include <cstddef>

typedef __hip_bfloat16 bf16;
using short8 = __attribute__((ext_vector_type(8))) short;
using f32x4  = __attribute__((ext_vector_type(4))) float;
using float4v = __attribute__((ext_vector_type(4))) float;
using uint4v  = __attribute__((ext_vector_type(4))) unsigned int;

__device__ __forceinline__ float s2f(short s) {
  unsigned u = ((unsigned)(unsigned short)s) << 16;
  return __builtin_bit_cast(float, u);
}
__device__ __forceinline__ short f2s(float f) {  // RNE f32->bf16
  unsigned u = __builtin_bit_cast(unsigned, f);
  u += 0x7fffu + ((u >> 16) & 1u);
  return (short)(u >> 16);
}
__device__ __forceinline__ float bclo(unsigned u) { return __builtin_bit_cast(float, u << 16); }
__device__ __forceinline__ float bchi(unsigned u) { return __builtin_bit_cast(float, u & 0xFFFF0000u); }

// ---------------- merged 1x1 conv + PReLU into zero-padded (+1 ring) f32 outputs ----
__global__ __launch_bounds__(256) void k_conv_all(
    const float* __restrict__ in_l, const float* __restrict__ in_s,
    const float* __restrict__ w_mlb, const float* __restrict__ b_mlb, const float* __restrict__ a_mlb,
    const float* __restrict__ w_m,   const float* __restrict__ b_m,   const float* __restrict__ a_m,
    const float* __restrict__ w_asm, const float* __restrict__ b_asm, const float* __restrict__ a_asm,
    float* __restrict__ MBpad, float* __restrict__ REFpad, float* __restrict__ BASEpad,
    int t1, int t2, int t3)
{
  int idx = blockIdx.x * 256 + threadIdx.x;
  const float *in, *w, *bi, *ap; float* o; int Cout, Hin, Win;
  if (idx < t1) { in = in_l; w = w_mlb; bi = b_mlb; ap = a_mlb; o = MBpad; Cout = 32; Hin = 96; Win = 96; }
  else if (idx < t1 + t2) { idx -= t1; in = in_s; w = w_m; bi = b_m; ap = a_m; o = REFpad; Cout = 32; Hin = 48; Win = 48; }
  else if (idx < t1 + t2 + t3) { idx -= t1 + t2; in = in_s; w = w_asm; bi = b_asm; ap = a_asm; o = BASEpad; Cout = 64; Hin = 48; Win = 48; }
  else return;
  int Wp = Win + 2, Hp = Hin + 2;
  int x = idx % Wp;
  int t = idx / Wp;
  int y = t % Hp; t /= Hp;
  int oc = t % Cout; int n = t / Cout;
  if (x == 0 || x == Wp - 1 || y == 0 || y == Hp - 1) { o[idx] = 0.0f; return; }
  int cs = Hin * Win;
  const float* ip = in + (size_t)n * 64 * cs + (size_t)(y - 1) * Win + (x - 1);
  const float* wp = w + oc * 64;
  float s = bi[oc];
#pragma unroll 16
  for (int ci = 0; ci < 64; ci++)
    s += wp[ci] * ip[(size_t)ci * cs];
  float a = ap[0];
  o[idx] = s >= 0.0f ? s : a * s;
}

// ---------------- merged gather/pack: Kp (stride 320) + Xp (stride 320) + Bb --------
__global__ __launch_bounds__(256) void k_gather_all(
    const float* __restrict__ mbpad, const float* __restrict__ refpad,
    const float* __restrict__ basepad,
    bf16* __restrict__ Kp, bf16* __restrict__ Xp, bf16* __restrict__ Bb)
{
  int b = blockIdx.x;
  int tid = threadIdx.x;
  if (b < 2304) {
    // key patches, L2-normalized, scale 10 folded; one wave per (n,l); stride 320
    int wid = b * 4 + (tid >> 6);
    int lane = tid & 63;
    int n = wid / 2304, l = wid % 2304, lh = l / 48, lw = l % 48;
    float v[5]; float ss = 0.f;
#pragma unroll
    for (int i = 0; i < 5; i++) {
      int k = lane + 64 * i; v[i] = 0.f;
      if (k < 288) {
        int c = k / 9, rr = (k % 9) / 3, sc = k % 3;
        v[i] = refpad[((size_t)(n * 32 + c) * 50 + lh + rr) * 50 + lw + sc];
        ss += v[i] * v[i];
      }
    }
#pragma unroll
    for (int off = 32; off; off >>= 1) ss += __shfl_xor(ss, off);
    float inv = 10.f / (sqrtf(ss) + 1e-4f);
#pragma unroll
    for (int i = 0; i < 5; i++) {
      int k = lane + 64 * i;
      Kp[(size_t)wid * 320 + k] = __float2bfloat16(k < 288 ? v[i] * inv : 0.f);
    }
  } else if (b < 2304 + 46080) {
    // query patches Xp[n][p][320]
    int idx = (b - 2304) * 256 + tid;
    int k = idx % 320; int p = (idx / 320) % 9216; int n = idx / (320 * 9216);
    float val = 0.f;
    if (k < 288) {
      int c = k / 9, rr = (k % 9) / 3, sc = k % 3;
      int ph = p / 96, pw = p % 96;
      val = mbpad[((size_t)(n * 32 + c) * 98 + ph + rr) * 98 + pw + sc];
    }
    Xp[idx] = __float2bfloat16(val);
  } else {
    // base value matrix Bb[n][o][l]
    int idx = (b - 48384) * 256 + tid;
    int l = idx % 2304; int o = (idx / 2304) % 64; int n = idx / (2304 * 64);
    int lh = l / 48, lw = l % 48;
    Bb[idx] = __float2bfloat16(basepad[((size_t)(n * 64 + o) * 50 + lh + 1) * 50 + lw + 1]);
  }
}

// ---------------- stage 1: QK tile GEMM + chunk-local softmax, writes P~ ------------
// block: 64q x 256l, 2x2 waves of 32q x 128l. 64-wide k-stages.
// vmcnt is FIFO: X (A-operand) fragments for the CURRENT stage are loaded FIRST
// (right after barrier B), then the 8 K-prefetch loads for stage s+1 are issued.
// Compute waits for X at vmcnt(8); the K loads stay outstanding until next stage's
// ds_write (a full compute phase of latency cover). X is single-buffered.
__global__ __launch_bounds__(256, 3) void k_qk(
    const bf16* __restrict__ Xp, const bf16* __restrict__ Kp,
    bf16* __restrict__ attnT, float* __restrict__ statsM, float* __restrict__ statsZ,
    int n, int qlo)
{
  __shared__ __align__(16) short KsPs[256 * 72];   // union: Ks 256x(64+8) / Ps 64x264
  __shared__ float Sm[2][2][32];
  __shared__ float Sz[2][2][32];
  int tid = threadIdx.x, lane = tid & 63, wv = tid >> 6;
  int quad = lane >> 4, m16 = lane & 15;
  int wr = wv >> 1, wc = wv & 1;
  int q0 = qlo + blockIdx.x * 64;
  int l0 = blockIdx.y * 256;

  f32x4 acc[2][8];
#pragma unroll
  for (int mi = 0; mi < 2; mi++)
#pragma unroll
    for (int t = 0; t < 8; t++) acc[mi][t] = (f32x4){0.f, 0.f, 0.f, 0.f};

  const short* Xrow = (const short*)Xp + ((size_t)n * 9216 + q0 + wr * 32 + m16) * 320;
  const short* Ksrc = (const short*)Kp + ((size_t)n * 2304 + l0) * 320;
  int srow = tid >> 2;            // 0..63 (rows srow + 64p)
  int scol = (tid & 3) * 16;      // 0,16,32,48

  // prologue: stage-0 K loads only
  short8 pf[8];
#pragma unroll
  for (int p = 0; p < 4; p++)
#pragma unroll
    for (int v = 0; v < 2; v++)
      pf[p * 2 + v] = *(const short8*)&Ksrc[(size_t)(srow + 64 * p) * 320 + scol + v * 8];

#pragma unroll
  for (int s = 0; s < 5; s++) {
    if (s) __syncthreads();       // (A) read->write hazard; drains pf(s) loads,
                                  //     which had all of compute(s-1) in flight
#pragma unroll
    for (int p = 0; p < 4; p++)
#pragma unroll
      for (int v = 0; v < 2; v++)
        *(short8*)&KsPs[(srow + 64 * p) * 72 + scol + v * 8] = pf[p * 2 + v];
    __syncthreads();              // (B) write->read hazard
    short8 xa0 = *(const short8*)&Xrow[s * 64 + quad * 8];
    short8 xa1 = *(const short8*)&Xrow[16 * 320 + s * 64 + quad * 8];
    short8 xa2 = *(const short8*)&Xrow[s * 64 + 32 + quad * 8];
    short8 xa3 = *(const short8*)&Xrow[16 * 320 + s * 64 + 32 + quad * 8];
    if (s < 4) {
      int kn = (s + 1) * 64;
#pragma unroll
      for (int p = 0; p < 4; p++)
#pragma unroll
        for (int v = 0; v < 2; v++)
          pf[p * 2 + v] = *(const short8*)&Ksrc[(size_t)(srow + 64 * p) * 320 + kn + scol + v * 8];
    }
#pragma unroll
    for (int half = 0; half < 2; half++) {
      int kc = s * 64 + half * 32;
      if (kc >= 288) break;       // K=288; skip zero tail
      short8 a0 = half ? xa2 : xa0;
      short8 a1 = half ? xa3 : xa1;
#pragma unroll
      for (int t = 0; t < 8; t++) {
        short8 bfr = *(const short8*)&KsPs[(wc * 128 + t * 16 + m16) * 72 + half * 32 + quad * 8];
        acc[0][t] = __builtin_amdgcn_mfma_f32_16x16x32_bf16(a0, bfr, acc[0][t], 0, 0, 0);
        acc[1][t] = __builtin_amdgcn_mfma_f32_16x16x32_bf16(a1, bfr, acc[1][t], 0, 0, 0);
      }
    }
  }

  // local stats over this wave's 128 l
  float mloc[2][4], zloc[2][4], scale[2][4];
#pragma unroll
  for (int mi = 0; mi < 2; mi++)
#pragma unroll
    for (int r = 0; r < 4; r++) mloc[mi][r] = -3.0e38f;
#pragma unroll
  for (int mi = 0; mi < 2; mi++)
#pragma unroll
    for (int t = 0; t < 8; t++)
#pragma unroll
      for (int r = 0; r < 4; r++) mloc[mi][r] = fmaxf(mloc[mi][r], acc[mi][t][r]);
#pragma unroll
  for (int off = 1; off < 16; off <<= 1)
#pragma unroll
    for (int mi = 0; mi < 2; mi++)
#pragma unroll
      for (int r = 0; r < 4; r++) mloc[mi][r] = fmaxf(mloc[mi][r], __shfl_xor(mloc[mi][r], off));
#pragma unroll
  for (int mi = 0; mi < 2; mi++)
#pragma unroll
    for (int r = 0; r < 4; r++) zloc[mi][r] = 0.f;
#pragma unroll
  for (int mi = 0; mi < 2; mi++)
#pragma unroll
    for (int t = 0; t < 8; t++)
#pragma unroll
      for (int r = 0; r < 4; r++) {
        float e = __expf(acc[mi][t][r] - mloc[mi][r]);
        acc[mi][t][r] = e;
        zloc[mi][r] += e;
      }
#pragma unroll
  for (int off = 1; off < 16; off <<= 1)
#pragma unroll
    for (int mi = 0; mi < 2; mi++)
#pragma unroll
      for (int r = 0; r < 4; r++) zloc[mi][r] += __shfl_xor(zloc[mi][r], off);
  if (m16 == 0) {
#pragma unroll
    for (int mi = 0; mi < 2; mi++)
#pragma unroll
      for (int r = 0; r < 4; r++) {
        int qi = mi * 16 + quad * 4 + r;
        Sm[wc][wr][qi] = mloc[mi][r];
        Sz[wc][wr][qi] = zloc[mi][r];
      }
  }
  __syncthreads();   // stats visible; also guards Ks reuse as Ps below
#pragma unroll
  for (int mi = 0; mi < 2; mi++)
#pragma unroll
    for (int r = 0; r < 4; r++) {
      int qi = mi * 16 + quad * 4 + r;
      float mo = Sm[wc ^ 1][wr][qi];
      float zo = Sz[wc ^ 1][wr][qi];
      float mc = fmaxf(mloc[mi][r], mo);
      float sc = __expf(mloc[mi][r] - mc);
      scale[mi][r] = sc;
      if (m16 == 0 && wc == 0) {
        float zc = zloc[mi][r] * sc + zo * __expf(mo - mc);
        int qq = q0 + wr * 32 + qi;
        statsM[blockIdx.y * 9216 + qq] = mc;
        statsZ[blockIdx.y * 9216 + qq] = zc;
      }
    }
  // write P~ tile through LDS (coalesced global stores)
#pragma unroll
  for (int mi = 0; mi < 2; mi++)
#pragma unroll
    for (int t = 0; t < 8; t++)
#pragma unroll
      for (int r = 0; r < 4; r++)
        KsPs[(wr * 32 + mi * 16 + quad * 4 + r) * 264 + wc * 128 + t * 16 + m16] =
            f2s(acc[mi][t][r] * scale[mi][r]);
  __syncthreads();
  {
    int row = tid >> 2, part = tid & 3;
    short* dst = (short*)attnT + (size_t)(q0 - qlo + row) * 2304 + l0 + part * 64;
    const short* sp = &KsPs[row * 264 + part * 64];
#pragma unroll
    for (int v = 0; v < 8; v++)
      *(short8*)&dst[v * 8] = *(const short8*)&sp[v * 8];
  }
}

// ---------------- stage 2: combine chunk stats -> alpha[c][q] ----------------
__global__ __launch_bounds__(256) void k_alpha(
    const float* __restrict__ statsM, const float* __restrict__ statsZ,
    float* __restrict__ alpha, int qlo, int qlen)
{
  int i = blockIdx.x * 256 + threadIdx.x;
  if (i >= qlen) return;
  int q = qlo + i;
  float M = -3.0e38f;
#pragma unroll
  for (int c = 0; c < 9; c++) M = fmaxf(M, statsM[c * 9216 + q]);
  float Z = 0.f;
#pragma unroll
  for (int c = 0; c < 9; c++) Z += statsZ[c * 9216 + q] * __expf(statsM[c * 9216 + q] - M);
  float invZ = 1.f / Z;
#pragma unroll
  for (int c = 0; c < 9; c++) alpha[c * 9216 + q] = __expf(statsM[c * 9216 + q] - M) * invZ;
}

// ---- stage 3: 9-point diagonal stencil with fused alpha, 16 l per thread ----------
// A2[l,q] = sum_d P~[l+dl, q+dq] * alpha[c(l+dl)][q+dq]
// aligned uint4 loads + funnel shifts; XCD-swizzled contiguous q bands.
__global__ __launch_bounds__(256) void k_a2(
    const bf16* __restrict__ attnT, const float* __restrict__ alpha,
    bf16* __restrict__ A2, int q0, int qlo)
{
  int bpx = gridDim.x >> 3;
  int nb = (blockIdx.x & 7) * bpx + (blockIdx.x >> 3);
  int g = nb * 256 + threadIdx.x;
  int qrel = g / 144;                 // 144 groups of 16 per q row
  int j = g - qrel * 144;
  int l0 = j * 16;
  int q = q0 + qrel;
  int h = q / 96, w = q - h * 96;
  int lh = l0 / 48, lw0 = l0 - lh * 48;   // 0,16,32 (16 | 48: never crosses lh rows)
  const short* att = (const short*)attnT;
  float acc[16];
#pragma unroll
  for (int k = 0; k < 16; k++) acc[k] = 0.f;
#pragma unroll
  for (int di = -1; di <= 1; di++) {
    int hh = h + di, lhh = lh + di;
    if (hh < 0 || hh >= 96 || lhh < 0 || lhh >= 48) continue;
    int lb = l0 + 48 * di;            // multiple of 16 -> 32B aligned
    int qv = q + 96 * di;
    const short* r0 = att + (size_t)(qv - qlo) * 2304;
    int c0 = lb >> 8;                 // 16-span never crosses a 256-chunk
    const float* alc = alpha + c0 * 9216;
    { // dj = 0
      float a = alc[qv];
      uint4v Va = *(const uint4v*)(r0 + lb);
      uint4v Vb = *(const uint4v*)(r0 + lb + 8);
#pragma unroll
      for (int k = 0; k < 4; k++) {
        acc[2 * k]      += bclo(Va[k]) * a;  acc[2 * k + 1]  += bchi(Va[k]) * a;
        acc[8 + 2 * k]  += bclo(Vb[k]) * a;  acc[9 + 2 * k]  += bchi(Vb[k]) * a;
      }
    }
    if (w > 0) { // dj = -1: shorts [lb-1 .. lb+14]; elem0 may be chunk c0-1
      const short* rm = r0 - 2304;
      int qp = qv - 1;
      float am = alc[qp];
      float a0 = ((lb & 255) == 0 && c0 > 0) ? alpha[(c0 - 1) * 9216 + qp] : am;
      uint4v Ma = *(const uint4v*)(rm + lb);
      uint4v Mb = *(const uint4v*)(rm + lb + 8);
      unsigned P = *(const unsigned*)(rm + lb - 2);
      unsigned D[8] = { Ma[0], Ma[1], Ma[2], Ma[3], Mb[0], Mb[1], Mb[2], Mb[3] };
      unsigned E0 = (P >> 16) | (D[0] << 16);
      if (lw0 == 0) E0 &= 0xFFFF0000u;     // elem0 would wrap to prev lh row
      acc[0] += bclo(E0) * a0;  acc[1] += bchi(E0) * am;
#pragma unroll
      for (int k = 1; k < 8; k++) {
        unsigned Ek = (D[k - 1] >> 16) | (D[k] << 16);
        acc[2 * k] += bclo(Ek) * am;  acc[2 * k + 1] += bchi(Ek) * am;
      }
    }
    if (w < 95) { // dj = +1: shorts [lb+1 .. lb+16]; elem15 may be chunk c0+1
      const short* rp = r0 + 2304;
      int qp = qv + 1;
      float am = alc[qp];
      float a15 = ((lb & 255) == 240 && c0 < 8) ? alpha[(c0 + 1) * 9216 + qp] : am;
      uint4v Pa = *(const uint4v*)(rp + lb);
      uint4v Pb = *(const uint4v*)(rp + lb + 8);
      unsigned N = *(const unsigned*)(rp + lb + 16);
      unsigned D[9] = { Pa[0], Pa[1], Pa[2], Pa[3], Pb[0], Pb[1], Pb[2], Pb[3], N };
      unsigned F7 = (D[7] >> 16) | (D[8] << 16);
      if (lw0 == 32) F7 &= 0x0000FFFFu;    // elem15 would wrap to next lh row
#pragma unroll
      for (int k = 0; k < 7; k++) {
        unsigned Fk = (D[k] >> 16) | (D[k + 1] << 16);
        acc[2 * k] += bclo(Fk) * am;  acc[2 * k + 1] += bchi(Fk) * am;
      }
      acc[14] += bclo(F7) * am;  acc[15] += bchi(F7) * a15;
    }
  }
  short8 o0, o1;
#pragma unroll
  for (int k = 0; k < 8; k++) { o0[k] = f2s(acc[k]); o1[k] = f2s(acc[8 + k]); }
  short* dst = (short*)A2 + (size_t)qrel * 2304 + l0;
  *(short8*)dst = o0;
  *(short8*)(dst + 8) = o1;
}

// ---- stage 4: PV GEMM, in-block split-K ------------------------------------------
// block = 16q x 64o; 4 waves each own 576 of K=2304 (no barriers in k-loop),
// LDS reduction, fused 0.25*C + residual epilogue. A2 streamed exactly once.
__global__ __launch_bounds__(256) void k_pv3(
    const bf16* __restrict__ A2, const bf16* __restrict__ Bb,
    const float* __restrict__ inl, float* __restrict__ out,
    int n, int q0base)
{
  __shared__ float Cred[4][16][67];
  int tid = threadIdx.x, lane = tid & 63, wv = tid >> 6;
  int quad = lane >> 4, m16 = lane & 15;
  int qb = blockIdx.x * 16;
  int kbase = wv * 576;
  f32x4 acc[4];
#pragma unroll
  for (int t = 0; t < 4; t++) acc[t] = (f32x4){0.f, 0.f, 0.f, 0.f};

  const short* Ap = (const short*)A2 + (size_t)qb * 2304 + kbase;
  const short* Bp = (const short*)Bb + (size_t)n * 64 * 2304 + kbase;

#pragma unroll
  for (int it = 0; it < 9; it++) {
    int kw = it * 64;
#pragma unroll
    for (int ks = 0; ks < 64; ks += 32) {
      short8 a = *(const short8*)&Ap[(size_t)m16 * 2304 + kw + ks + quad * 8];
#pragma unroll
      for (int ni = 0; ni < 4; ni++) {
        short8 b = *(const short8*)&Bp[(size_t)(ni * 16 + m16) * 2304 + kw + ks + quad * 8];
        acc[ni] = __builtin_amdgcn_mfma_f32_16x16x32_bf16(a, b, acc[ni], 0, 0, 0);
      }
    }
  }
#pragma unroll
  for (int ni = 0; ni < 4; ni++)
#pragma unroll
    for (int r = 0; r < 4; r++)
      Cred[wv][quad * 4 + r][ni * 16 + m16] = acc[ni][r];
  __syncthreads();
  {
    int o = tid >> 2;                // 0..63
    int qg = (tid & 3) * 4;          // 0..12
    float4v s;
#pragma unroll
    for (int j = 0; j < 4; j++)
      s[j] = Cred[0][qg + j][o] + Cred[1][qg + j][o] + Cred[2][qg + j][o] + Cred[3][qg + j][o];
    size_t oid = ((size_t)(n * 64 + o)) * 9216 + q0base + qb + qg;
    float4v r4 = *(const float4v*)&inl[oid];
    float4v y;
#pragma unroll
    for (int j = 0; j < 4; j++) y[j] = 0.25f * s[j] + r4[j];
    *(float4v*)&out[oid] = y;
  }
}

extern "C" void kernel_launch(void* const* d_in, const int* in_sizes, int n_in,
                              void* d_out, int out_size, void* d_ws, size_t ws_size,
                              hipStream_t stream)
{
  (void)in_sizes; (void)n_in; (void)out_size;
  const float* input_l = (const float*)d_in[0];
  const float* input_s = (const float*)d_in[1];
  const float* w_mlb = (const float*)d_in[2];
  const float* b_mlb = (const float*)d_in[3];
  const float* a_mlb = (const float*)d_in[4];
  const float* w_m   = (const float*)d_in[5];
  const float* b_m   = (const float*)d_in[6];
  const float* a_m   = (const float*)d_in[7];
  const float* w_asm = (const float*)d_in[8];
  const float* b_asm = (const float*)d_in[9];
  const float* a_asm = (const float*)d_in[10];
  float* out = (float*)d_out;

  char* base = (char*)d_ws;
  size_t off = 0;
  auto carve = [&](size_t bytes) -> char* {
    char* r = base + off;
    off += (bytes + 255) & ~(size_t)255;
    return r;
  };

  float* MBpad   = (float*)carve((size_t)4 * 32 * 98 * 98 * 4);
  float* REFpad  = (float*)carve((size_t)4 * 32 * 50 * 50 * 4);
  float* BASEpad = (float*)carve((size_t)4 * 64 * 50 * 50 * 4);
  bf16*  Kp      = (bf16*)carve((size_t)4 * 2304 * 320 * 2);
  bf16*  Xp      = (bf16*)carve((size_t)4 * 9216 * 320 * 2);
  bf16*  Bb      = (bf16*)carve((size_t)4 * 64 * 2304 * 2);
  float* statsM  = (float*)carve((size_t)9 * 9216 * 4);
  float* statsZ  = (float*)carve((size_t)9 * 9216 * 4);
  float* alpha   = (float*)carve((size_t)9 * 9216 * 4);
  size_t fixedOff = off;

  auto need = [&](int qmax, int psplit) -> size_t {
    size_t a = ((size_t)qmax * 2304 * 2 + 255) & ~(size_t)255;
    size_t b2 = ((size_t)psplit * 2304 * 2 + 255) & ~(size_t)255;
    return fixedOff + a + b2;
  };
  int nsplit, qmax, psplit;
  if (need(9216, 9216) <= ws_size)      { nsplit = 1; qmax = 9216; psplit = 9216; }
  else if (need(5120, 4608) <= ws_size) { nsplit = 2; qmax = 5120; psplit = 4608; }
  else                                  { nsplit = 4; qmax = 2816; psplit = 2304; }

  bf16* attnT = (bf16*)carve((size_t)qmax * 2304 * 2);
  bf16* A2    = (bf16*)carve((size_t)psplit * 2304 * 2);

  // ---- prep (all samples, 2 dispatches) ----
  {
    int t1 = 4 * 32 * 98 * 98;
    int t2 = 4 * 32 * 50 * 50;
    int t3 = 4 * 64 * 50 * 50;
    int tt = t1 + t2 + t3;
    k_conv_all<<<dim3((tt + 255) / 256), dim3(256), 0, stream>>>(
        input_l, input_s, w_mlb, b_mlb, a_mlb, w_m, b_m, a_m, w_asm, b_asm, a_asm,
        MBpad, REFpad, BASEpad, t1, t2, t3);
    k_gather_all<<<dim3(2304 + 46080 + 2304), dim3(256), 0, stream>>>(
        MBpad, REFpad, BASEpad, Kp, Xp, Bb);
  }

  // ---- attention per (sample, query band) ----
  for (int n = 0; n < 4; n++) {
    for (int s = 0; s < nsplit; s++) {
      int q0 = s * psplit;
      int qlo = q0 - 256; if (qlo < 0) qlo = 0;
      int qhi = q0 + psplit + 256; if (qhi > 9216) qhi = 9216;
      int qlen = qhi - qlo;  // multiple of 256 by construction
      k_qk<<<dim3(qlen / 64, 9), dim3(256), 0, stream>>>(Xp, Kp, attnT, statsM, statsZ, n, qlo);
      k_alpha<<<dim3(qlen / 256), dim3(256), 0, stream>>>(statsM, statsZ, alpha, qlo, qlen);
      k_a2<<<dim3(psplit * 144 / 256), dim3(256), 0, stream>>>(attnT, alpha, A2, q0, qlo);
      k_pv3<<<dim3(psplit / 16), dim3(256), 0, stream>>>(A2, Bb, input_l, out, n, q0);
    }
  }
}

// Round 9
// 526.548 us; speedup vs baseline: 1.4977x; 1.1087x over previous
//
#include <hip/hip_runtime.h>
#include <hip/hip_bf16.h>
#include <cstdint>
#include <cstddef>

typedef __hip_bfloat16 bf16;
using short8 = __attribute__((ext_vector_type(8))) short;
using f32x4  = __attribute__((ext_vector_type(4))) float;
using float4v = __attribute__((ext_vector_type(4))) float;
using uint4v  = __attribute__((ext_vector_type(4))) unsigned int;

__device__ __forceinline__ float s2f(short s) {
  unsigned u = ((unsigned)(unsigned short)s) << 16;
  return __builtin_bit_cast(float, u);
}
__device__ __forceinline__ short f2s(float f) {  // RNE f32->bf16
  unsigned u = __builtin_bit_cast(unsigned, f);
  u += 0x7fffu + ((u >> 16) & 1u);
  return (short)(u >> 16);
}
__device__ __forceinline__ float bclo(unsigned u) { return __builtin_bit_cast(float, u << 16); }
__device__ __forceinline__ float bchi(unsigned u) { return __builtin_bit_cast(float, u & 0xFFFF0000u); }

// ---------------- merged 1x1 conv + PReLU into zero-padded (+1 ring) f32 outputs ----
__global__ __launch_bounds__(256) void k_conv_all(
    const float* __restrict__ in_l, const float* __restrict__ in_s,
    const float* __restrict__ w_mlb, const float* __restrict__ b_mlb, const float* __restrict__ a_mlb,
    const float* __restrict__ w_m,   const float* __restrict__ b_m,   const float* __restrict__ a_m,
    const float* __restrict__ w_asm, const float* __restrict__ b_asm, const float* __restrict__ a_asm,
    float* __restrict__ MBpad, float* __restrict__ REFpad, float* __restrict__ BASEpad,
    int t1, int t2, int t3)
{
  int idx = blockIdx.x * 256 + threadIdx.x;
  const float *in, *w, *bi, *ap; float* o; int Cout, Hin, Win;
  if (idx < t1) { in = in_l; w = w_mlb; bi = b_mlb; ap = a_mlb; o = MBpad; Cout = 32; Hin = 96; Win = 96; }
  else if (idx < t1 + t2) { idx -= t1; in = in_s; w = w_m; bi = b_m; ap = a_m; o = REFpad; Cout = 32; Hin = 48; Win = 48; }
  else if (idx < t1 + t2 + t3) { idx -= t1 + t2; in = in_s; w = w_asm; bi = b_asm; ap = a_asm; o = BASEpad; Cout = 64; Hin = 48; Win = 48; }
  else return;
  int Wp = Win + 2, Hp = Hin + 2;
  int x = idx % Wp;
  int t = idx / Wp;
  int y = t % Hp; t /= Hp;
  int oc = t % Cout; int n = t / Cout;
  if (x == 0 || x == Wp - 1 || y == 0 || y == Hp - 1) { o[idx] = 0.0f; return; }
  int cs = Hin * Win;
  const float* ip = in + (size_t)n * 64 * cs + (size_t)(y - 1) * Win + (x - 1);
  const float* wp = w + oc * 64;
  float s = bi[oc];
#pragma unroll 16
  for (int ci = 0; ci < 64; ci++)
    s += wp[ci] * ip[(size_t)ci * cs];
  float a = ap[0];
  o[idx] = s >= 0.0f ? s : a * s;
}

// ---------------- merged gather/pack: Kp (stride 320) + Xp (stride 320) + Bb --------
__global__ __launch_bounds__(256) void k_gather_all(
    const float* __restrict__ mbpad, const float* __restrict__ refpad,
    const float* __restrict__ basepad,
    bf16* __restrict__ Kp, bf16* __restrict__ Xp, bf16* __restrict__ Bb)
{
  int b = blockIdx.x;
  int tid = threadIdx.x;
  if (b < 2304) {
    // key patches, L2-normalized, scale 10 folded; one wave per (n,l); stride 320
    int wid = b * 4 + (tid >> 6);
    int lane = tid & 63;
    int n = wid / 2304, l = wid % 2304, lh = l / 48, lw = l % 48;
    float v[5]; float ss = 0.f;
#pragma unroll
    for (int i = 0; i < 5; i++) {
      int k = lane + 64 * i; v[i] = 0.f;
      if (k < 288) {
        int c = k / 9, rr = (k % 9) / 3, sc = k % 3;
        v[i] = refpad[((size_t)(n * 32 + c) * 50 + lh + rr) * 50 + lw + sc];
        ss += v[i] * v[i];
      }
    }
#pragma unroll
    for (int off = 32; off; off >>= 1) ss += __shfl_xor(ss, off);
    float inv = 10.f / (sqrtf(ss) + 1e-4f);
#pragma unroll
    for (int i = 0; i < 5; i++) {
      int k = lane + 64 * i;
      Kp[(size_t)wid * 320 + k] = __float2bfloat16(k < 288 ? v[i] * inv : 0.f);
    }
  } else if (b < 2304 + 46080) {
    // query patches Xp[n][p][320]
    int idx = (b - 2304) * 256 + tid;
    int k = idx % 320; int p = (idx / 320) % 9216; int n = idx / (320 * 9216);
    float val = 0.f;
    if (k < 288) {
      int c = k / 9, rr = (k % 9) / 3, sc = k % 3;
      int ph = p / 96, pw = p % 96;
      val = mbpad[((size_t)(n * 32 + c) * 98 + ph + rr) * 98 + pw + sc];
    }
    Xp[idx] = __float2bfloat16(val);
  } else {
    // base value matrix Bb[n][o][l]
    int idx = (b - 48384) * 256 + tid;
    int l = idx % 2304; int o = (idx / 2304) % 64; int n = idx / (2304 * 64);
    int lh = l / 48, lw = l % 48;
    Bb[idx] = __float2bfloat16(basepad[((size_t)(n * 64 + o) * 50 + lh + 1) * 50 + lw + 1]);
  }
}

// ---------------- stage 1: QK tile GEMM + chunk-local softmax, writes P~ ------------
// block: 64q x 256l, 2x2 waves of 32q x 128l. 64-wide k-stages.
// vmcnt is FIFO: X (A-operand) fragments for the CURRENT stage are loaded FIRST
// (right after barrier B), then the 8 K-prefetch loads for stage s+1 are issued.
// Compute waits for X at vmcnt(8); the K loads stay outstanding until next stage's
// ds_write (a full compute phase of latency cover). X is single-buffered.
// blockIdx.z = sample-within-batch (z=0 in fallback mode -> offsets vanish).
__global__ __launch_bounds__(256, 3) void k_qk(
    const bf16* __restrict__ Xp, const bf16* __restrict__ Kp,
    bf16* __restrict__ attnT, float* __restrict__ statsM, float* __restrict__ statsZ,
    int nbase, int qlo)
{
  __shared__ __align__(16) short KsPs[256 * 72];   // union: Ks 256x(64+8) / Ps 64x264
  __shared__ float Sm[2][2][32];
  __shared__ float Sz[2][2][32];
  int z = blockIdx.z;
  int n = nbase + z;
  attnT += (size_t)z * 9216 * 2304;      // batched mode: full-size per-sample rows
  statsM += (size_t)z * 9 * 9216;
  statsZ += (size_t)z * 9 * 9216;
  int tid = threadIdx.x, lane = tid & 63, wv = tid >> 6;
  int quad = lane >> 4, m16 = lane & 15;
  int wr = wv >> 1, wc = wv & 1;
  int q0 = qlo + blockIdx.x * 64;
  int l0 = blockIdx.y * 256;

  f32x4 acc[2][8];
#pragma unroll
  for (int mi = 0; mi < 2; mi++)
#pragma unroll
    for (int t = 0; t < 8; t++) acc[mi][t] = (f32x4){0.f, 0.f, 0.f, 0.f};

  const short* Xrow = (const short*)Xp + ((size_t)n * 9216 + q0 + wr * 32 + m16) * 320;
  const short* Ksrc = (const short*)Kp + ((size_t)n * 2304 + l0) * 320;
  int srow = tid >> 2;            // 0..63 (rows srow + 64p)
  int scol = (tid & 3) * 16;      // 0,16,32,48

  // prologue: stage-0 K loads only
  short8 pf[8];
#pragma unroll
  for (int p = 0; p < 4; p++)
#pragma unroll
    for (int v = 0; v < 2; v++)
      pf[p * 2 + v] = *(const short8*)&Ksrc[(size_t)(srow + 64 * p) * 320 + scol + v * 8];

#pragma unroll
  for (int s = 0; s < 5; s++) {
    if (s) __syncthreads();       // (A) read->write hazard; drains pf(s) loads,
                                  //     which had all of compute(s-1) in flight
#pragma unroll
    for (int p = 0; p < 4; p++)
#pragma unroll
      for (int v = 0; v < 2; v++)
        *(short8*)&KsPs[(srow + 64 * p) * 72 + scol + v * 8] = pf[p * 2 + v];
    __syncthreads();              // (B) write->read hazard
    short8 xa0 = *(const short8*)&Xrow[s * 64 + quad * 8];
    short8 xa1 = *(const short8*)&Xrow[16 * 320 + s * 64 + quad * 8];
    short8 xa2 = *(const short8*)&Xrow[s * 64 + 32 + quad * 8];
    short8 xa3 = *(const short8*)&Xrow[16 * 320 + s * 64 + 32 + quad * 8];
    if (s < 4) {
      int kn = (s + 1) * 64;
#pragma unroll
      for (int p = 0; p < 4; p++)
#pragma unroll
        for (int v = 0; v < 2; v++)
          pf[p * 2 + v] = *(const short8*)&Ksrc[(size_t)(srow + 64 * p) * 320 + kn + scol + v * 8];
    }
#pragma unroll
    for (int half = 0; half < 2; half++) {
      int kc = s * 64 + half * 32;
      if (kc >= 288) break;       // K=288; skip zero tail
      short8 a0 = half ? xa2 : xa0;
      short8 a1 = half ? xa3 : xa1;
#pragma unroll
      for (int t = 0; t < 8; t++) {
        short8 bfr = *(const short8*)&KsPs[(wc * 128 + t * 16 + m16) * 72 + half * 32 + quad * 8];
        acc[0][t] = __builtin_amdgcn_mfma_f32_16x16x32_bf16(a0, bfr, acc[0][t], 0, 0, 0);
        acc[1][t] = __builtin_amdgcn_mfma_f32_16x16x32_bf16(a1, bfr, acc[1][t], 0, 0, 0);
      }
    }
  }

  // local stats over this wave's 128 l
  float mloc[2][4], zloc[2][4], scale[2][4];
#pragma unroll
  for (int mi = 0; mi < 2; mi++)
#pragma unroll
    for (int r = 0; r < 4; r++) mloc[mi][r] = -3.0e38f;
#pragma unroll
  for (int mi = 0; mi < 2; mi++)
#pragma unroll
    for (int t = 0; t < 8; t++)
#pragma unroll
      for (int r = 0; r < 4; r++) mloc[mi][r] = fmaxf(mloc[mi][r], acc[mi][t][r]);
#pragma unroll
  for (int off = 1; off < 16; off <<= 1)
#pragma unroll
    for (int mi = 0; mi < 2; mi++)
#pragma unroll
      for (int r = 0; r < 4; r++) mloc[mi][r] = fmaxf(mloc[mi][r], __shfl_xor(mloc[mi][r], off));
#pragma unroll
  for (int mi = 0; mi < 2; mi++)
#pragma unroll
    for (int r = 0; r < 4; r++) zloc[mi][r] = 0.f;
#pragma unroll
  for (int mi = 0; mi < 2; mi++)
#pragma unroll
    for (int t = 0; t < 8; t++)
#pragma unroll
      for (int r = 0; r < 4; r++) {
        float e = __expf(acc[mi][t][r] - mloc[mi][r]);
        acc[mi][t][r] = e;
        zloc[mi][r] += e;
      }
#pragma unroll
  for (int off = 1; off < 16; off <<= 1)
#pragma unroll
    for (int mi = 0; mi < 2; mi++)
#pragma unroll
      for (int r = 0; r < 4; r++) zloc[mi][r] += __shfl_xor(zloc[mi][r], off);
  if (m16 == 0) {
#pragma unroll
    for (int mi = 0; mi < 2; mi++)
#pragma unroll
      for (int r = 0; r < 4; r++) {
        int qi = mi * 16 + quad * 4 + r;
        Sm[wc][wr][qi] = mloc[mi][r];
        Sz[wc][wr][qi] = zloc[mi][r];
      }
  }
  __syncthreads();   // stats visible; also guards Ks reuse as Ps below
#pragma unroll
  for (int mi = 0; mi < 2; mi++)
#pragma unroll
    for (int r = 0; r < 4; r++) {
      int qi = mi * 16 + quad * 4 + r;
      float mo = Sm[wc ^ 1][wr][qi];
      float zo = Sz[wc ^ 1][wr][qi];
      float mc = fmaxf(mloc[mi][r], mo);
      float sc = __expf(mloc[mi][r] - mc);
      scale[mi][r] = sc;
      if (m16 == 0 && wc == 0) {
        float zc = zloc[mi][r] * sc + zo * __expf(mo - mc);
        int qq = q0 + wr * 32 + qi;
        statsM[blockIdx.y * 9216 + qq] = mc;
        statsZ[blockIdx.y * 9216 + qq] = zc;
      }
    }
  // write P~ tile through LDS (coalesced global stores)
#pragma unroll
  for (int mi = 0; mi < 2; mi++)
#pragma unroll
    for (int t = 0; t < 8; t++)
#pragma unroll
      for (int r = 0; r < 4; r++)
        KsPs[(wr * 32 + mi * 16 + quad * 4 + r) * 264 + wc * 128 + t * 16 + m16] =
            f2s(acc[mi][t][r] * scale[mi][r]);
  __syncthreads();
  {
    int row = tid >> 2, part = tid & 3;
    short* dst = (short*)attnT + (size_t)(q0 - qlo + row) * 2304 + l0 + part * 64;
    const short* sp = &KsPs[row * 264 + part * 64];
#pragma unroll
    for (int v = 0; v < 8; v++)
      *(short8*)&dst[v * 8] = *(const short8*)&sp[v * 8];
  }
}

// ---------------- stage 2: combine chunk stats -> alpha[c][q] ----------------
// blockIdx.y = sample-within-batch.
__global__ __launch_bounds__(256) void k_alpha(
    const float* __restrict__ statsM, const float* __restrict__ statsZ,
    float* __restrict__ alpha, int qlo, int qlen)
{
  int z = blockIdx.y;
  statsM += (size_t)z * 9 * 9216;
  statsZ += (size_t)z * 9 * 9216;
  alpha  += (size_t)z * 9 * 9216;
  int i = blockIdx.x * 256 + threadIdx.x;
  if (i >= qlen) return;
  int q = qlo + i;
  float M = -3.0e38f;
#pragma unroll
  for (int c = 0; c < 9; c++) M = fmaxf(M, statsM[c * 9216 + q]);
  float Z = 0.f;
#pragma unroll
  for (int c = 0; c < 9; c++) Z += statsZ[c * 9216 + q] * __expf(statsM[c * 9216 + q] - M);
  float invZ = 1.f / Z;
#pragma unroll
  for (int c = 0; c < 9; c++) alpha[c * 9216 + q] = __expf(statsM[c * 9216 + q] - M) * invZ;
}

// ---- stage 3: 9-point diagonal stencil with fused alpha, 16 l per thread ----------
// A2[l,q] = sum_d P~[l+dl, q+dq] * alpha[c(l+dl)][q+dq]
// aligned uint4 loads + funnel shifts; XCD-swizzled contiguous q bands.
// blockIdx.z = sample-within-batch.
__global__ __launch_bounds__(256) void k_a2(
    const bf16* __restrict__ attnT, const float* __restrict__ alpha,
    bf16* __restrict__ A2, int q0, int qlo)
{
  int z = blockIdx.z;
  attnT += (size_t)z * 9216 * 2304;
  alpha += (size_t)z * 9 * 9216;
  A2    += (size_t)z * 9216 * 2304;
  int bpx = gridDim.x >> 3;
  int nb = (blockIdx.x & 7) * bpx + (blockIdx.x >> 3);
  int g = nb * 256 + threadIdx.x;
  int qrel = g / 144;                 // 144 groups of 16 per q row
  int j = g - qrel * 144;
  int l0 = j * 16;
  int q = q0 + qrel;
  int h = q / 96, w = q - h * 96;
  int lh = l0 / 48, lw0 = l0 - lh * 48;   // 0,16,32 (16 | 48: never crosses lh rows)
  const short* att = (const short*)attnT;
  float acc[16];
#pragma unroll
  for (int k = 0; k < 16; k++) acc[k] = 0.f;
#pragma unroll
  for (int di = -1; di <= 1; di++) {
    int hh = h + di, lhh = lh + di;
    if (hh < 0 || hh >= 96 || lhh < 0 || lhh >= 48) continue;
    int lb = l0 + 48 * di;            // multiple of 16 -> 32B aligned
    int qv = q + 96 * di;
    const short* r0 = att + (size_t)(qv - qlo) * 2304;
    int c0 = lb >> 8;                 // 16-span never crosses a 256-chunk
    const float* alc = alpha + c0 * 9216;
    { // dj = 0
      float a = alc[qv];
      uint4v Va = *(const uint4v*)(r0 + lb);
      uint4v Vb = *(const uint4v*)(r0 + lb + 8);
#pragma unroll
      for (int k = 0; k < 4; k++) {
        acc[2 * k]      += bclo(Va[k]) * a;  acc[2 * k + 1]  += bchi(Va[k]) * a;
        acc[8 + 2 * k]  += bclo(Vb[k]) * a;  acc[9 + 2 * k]  += bchi(Vb[k]) * a;
      }
    }
    if (w > 0) { // dj = -1: shorts [lb-1 .. lb+14]; elem0 may be chunk c0-1
      const short* rm = r0 - 2304;
      int qp = qv - 1;
      float am = alc[qp];
      float a0 = ((lb & 255) == 0 && c0 > 0) ? alpha[(c0 - 1) * 9216 + qp] : am;
      uint4v Ma = *(const uint4v*)(rm + lb);
      uint4v Mb = *(const uint4v*)(rm + lb + 8);
      unsigned P = *(const unsigned*)(rm + lb - 2);
      unsigned D[8] = { Ma[0], Ma[1], Ma[2], Ma[3], Mb[0], Mb[1], Mb[2], Mb[3] };
      unsigned E0 = (P >> 16) | (D[0] << 16);
      if (lw0 == 0) E0 &= 0xFFFF0000u;     // elem0 would wrap to prev lh row
      acc[0] += bclo(E0) * a0;  acc[1] += bchi(E0) * am;
#pragma unroll
      for (int k = 1; k < 8; k++) {
        unsigned Ek = (D[k - 1] >> 16) | (D[k] << 16);
        acc[2 * k] += bclo(Ek) * am;  acc[2 * k + 1] += bchi(Ek) * am;
      }
    }
    if (w < 95) { // dj = +1: shorts [lb+1 .. lb+16]; elem15 may be chunk c0+1
      const short* rp = r0 + 2304;
      int qp = qv + 1;
      float am = alc[qp];
      float a15 = ((lb & 255) == 240 && c0 < 8) ? alpha[(c0 + 1) * 9216 + qp] : am;
      uint4v Pa = *(const uint4v*)(rp + lb);
      uint4v Pb = *(const uint4v*)(rp + lb + 8);
      unsigned N = *(const unsigned*)(rp + lb + 16);
      unsigned D[9] = { Pa[0], Pa[1], Pa[2], Pa[3], Pb[0], Pb[1], Pb[2], Pb[3], N };
      unsigned F7 = (D[7] >> 16) | (D[8] << 16);
      if (lw0 == 32) F7 &= 0x0000FFFFu;    // elem15 would wrap to next lh row
#pragma unroll
      for (int k = 0; k < 7; k++) {
        unsigned Fk = (D[k] >> 16) | (D[k + 1] << 16);
        acc[2 * k] += bclo(Fk) * am;  acc[2 * k + 1] += bchi(Fk) * am;
      }
      acc[14] += bclo(F7) * am;  acc[15] += bchi(F7) * a15;
    }
  }
  short8 o0, o1;
#pragma unroll
  for (int k = 0; k < 8; k++) { o0[k] = f2s(acc[k]); o1[k] = f2s(acc[8 + k]); }
  short* dst = (short*)A2 + (size_t)qrel * 2304 + l0;
  *(short8*)dst = o0;
  *(short8*)(dst + 8) = o1;
}

// ---- stage 4: PV GEMM, in-block split-K ------------------------------------------
// block = 16q x 64o; 4 waves each own 576 of K=2304 (no barriers in k-loop),
// LDS reduction, fused 0.25*C + residual epilogue. A2 streamed exactly once.
// blockIdx.z = sample-within-batch.
__global__ __launch_bounds__(256) void k_pv3(
    const bf16* __restrict__ A2, const bf16* __restrict__ Bb,
    const float* __restrict__ inl, float* __restrict__ out,
    int nbase, int q0base)
{
  __shared__ float Cred[4][16][67];
  int z = blockIdx.z;
  int n = nbase + z;
  A2 += (size_t)z * 9216 * 2304;
  int tid = threadIdx.x, lane = tid & 63, wv = tid >> 6;
  int quad = lane >> 4, m16 = lane & 15;
  int qb = blockIdx.x * 16;
  int kbase = wv * 576;
  f32x4 acc[4];
#pragma unroll
  for (int t = 0; t < 4; t++) acc[t] = (f32x4){0.f, 0.f, 0.f, 0.f};

  const short* Ap = (const short*)A2 + (size_t)qb * 2304 + kbase;
  const short* Bp = (const short*)Bb + (size_t)n * 64 * 2304 + kbase;

#pragma unroll
  for (int it = 0; it < 9; it++) {
    int kw = it * 64;
#pragma unroll
    for (int ks = 0; ks < 64; ks += 32) {
      short8 a = *(const short8*)&Ap[(size_t)m16 * 2304 + kw + ks + quad * 8];
#pragma unroll
      for (int ni = 0; ni < 4; ni++) {
        short8 b = *(const short8*)&Bp[(size_t)(ni * 16 + m16) * 2304 + kw + ks + quad * 8];
        acc[ni] = __builtin_amdgcn_mfma_f32_16x16x32_bf16(a, b, acc[ni], 0, 0, 0);
      }
    }
  }
#pragma unroll
  for (int ni = 0; ni < 4; ni++)
#pragma unroll
    for (int r = 0; r < 4; r++)
      Cred[wv][quad * 4 + r][ni * 16 + m16] = acc[ni][r];
  __syncthreads();
  {
    int o = tid >> 2;                // 0..63
    int qg = (tid & 3) * 4;          // 0..12
    float4v s;
#pragma unroll
    for (int j = 0; j < 4; j++)
      s[j] = Cred[0][qg + j][o] + Cred[1][qg + j][o] + Cred[2][qg + j][o] + Cred[3][qg + j][o];
    size_t oid = ((size_t)(n * 64 + o)) * 9216 + q0base + qb + qg;
    float4v r4 = *(const float4v*)&inl[oid];
    float4v y;
#pragma unroll
    for (int j = 0; j < 4; j++) y[j] = 0.25f * s[j] + r4[j];
    *(float4v*)&out[oid] = y;
  }
}

extern "C" void kernel_launch(void* const* d_in, const int* in_sizes, int n_in,
                              void* d_out, int out_size, void* d_ws, size_t ws_size,
                              hipStream_t stream)
{
  (void)in_sizes; (void)n_in; (void)out_size;
  const float* input_l = (const float*)d_in[0];
  const float* input_s = (const float*)d_in[1];
  const float* w_mlb = (const float*)d_in[2];
  const float* b_mlb = (const float*)d_in[3];
  const float* a_mlb = (const float*)d_in[4];
  const float* w_m   = (const float*)d_in[5];
  const float* b_m   = (const float*)d_in[6];
  const float* a_m   = (const float*)d_in[7];
  const float* w_asm = (const float*)d_in[8];
  const float* b_asm = (const float*)d_in[9];
  const float* a_asm = (const float*)d_in[10];
  float* out = (float*)d_out;

  char* base = (char*)d_ws;
  size_t off = 0;
  auto carve = [&](size_t bytes) -> char* {
    char* r = base + off;
    off += (bytes + 255) & ~(size_t)255;
    return r;
  };

  float* MBpad   = (float*)carve((size_t)4 * 32 * 98 * 98 * 4);
  float* REFpad  = (float*)carve((size_t)4 * 32 * 50 * 50 * 4);
  float* BASEpad = (float*)carve((size_t)4 * 64 * 50 * 50 * 4);
  bf16*  Kp      = (bf16*)carve((size_t)4 * 2304 * 320 * 2);
  bf16*  Xp      = (bf16*)carve((size_t)4 * 9216 * 320 * 2);
  bf16*  Bb      = (bf16*)carve((size_t)4 * 64 * 2304 * 2);
  float* statsM  = (float*)carve((size_t)2 * 9 * 9216 * 4);   // x2 for paired batch
  float* statsZ  = (float*)carve((size_t)2 * 9 * 9216 * 4);
  float* alpha   = (float*)carve((size_t)2 * 9 * 9216 * 4);
  size_t fixedOff = off;

  auto need = [&](int qmax, int psplit, int B) -> size_t {
    size_t a = (((size_t)qmax * 2304 * 2) * B + 255) & ~(size_t)255;
    size_t b2 = (((size_t)psplit * 2304 * 2) * B + 255) & ~(size_t)255;
    return fixedOff + a + b2;
  };
  int nsplit, qmax, psplit, batchB;
  if (need(9216, 9216, 2) <= ws_size)      { batchB = 2; nsplit = 1; qmax = 9216; psplit = 9216; }
  else if (need(9216, 9216, 1) <= ws_size) { batchB = 1; nsplit = 1; qmax = 9216; psplit = 9216; }
  else if (need(5120, 4608, 1) <= ws_size) { batchB = 1; nsplit = 2; qmax = 5120; psplit = 4608; }
  else                                     { batchB = 1; nsplit = 4; qmax = 2816; psplit = 2304; }

  bf16* attnT = (bf16*)carve((size_t)qmax * 2304 * 2 * batchB);
  bf16* A2    = (bf16*)carve((size_t)psplit * 2304 * 2 * batchB);

  // ---- prep (all samples, 2 dispatches) ----
  {
    int t1 = 4 * 32 * 98 * 98;
    int t2 = 4 * 32 * 50 * 50;
    int t3 = 4 * 64 * 50 * 50;
    int tt = t1 + t2 + t3;
    k_conv_all<<<dim3((tt + 255) / 256), dim3(256), 0, stream>>>(
        input_l, input_s, w_mlb, b_mlb, a_mlb, w_m, b_m, a_m, w_asm, b_asm, a_asm,
        MBpad, REFpad, BASEpad, t1, t2, t3);
    k_gather_all<<<dim3(2304 + 46080 + 2304), dim3(256), 0, stream>>>(
        MBpad, REFpad, BASEpad, Kp, Xp, Bb);
  }

  if (batchB == 2) {
    // ---- paired-sample batching: 8 attention dispatches total ----
    for (int p = 0; p < 2; p++) {
      int nb = p * 2;
      k_qk<<<dim3(144, 9, 2), dim3(256), 0, stream>>>(Xp, Kp, attnT, statsM, statsZ, nb, 0);
      k_alpha<<<dim3(36, 2), dim3(256), 0, stream>>>(statsM, statsZ, alpha, 0, 9216);
      k_a2<<<dim3(5184, 1, 2), dim3(256), 0, stream>>>(attnT, alpha, A2, 0, 0);
      k_pv3<<<dim3(576, 1, 2), dim3(256), 0, stream>>>(A2, Bb, input_l, out, nb, 0);
    }
  } else {
    // ---- fallback: per (sample, query band), z = 0 everywhere ----
    for (int n = 0; n < 4; n++) {
      for (int s = 0; s < nsplit; s++) {
        int q0 = s * psplit;
        int qlo = q0 - 256; if (qlo < 0) qlo = 0;
        int qhi = q0 + psplit + 256; if (qhi > 9216) qhi = 9216;
        int qlen = qhi - qlo;  // multiple of 256 by construction
        k_qk<<<dim3(qlen / 64, 9, 1), dim3(256), 0, stream>>>(Xp, Kp, attnT, statsM, statsZ, n, qlo);
        k_alpha<<<dim3(qlen / 256, 1), dim3(256), 0, stream>>>(statsM, statsZ, alpha, qlo, qlen);
        k_a2<<<dim3(psplit * 144 / 256, 1, 1), dim3(256), 0, stream>>>(attnT, alpha, A2, q0, qlo);
        k_pv3<<<dim3(psplit / 16, 1, 1), dim3(256), 0, stream>>>(A2, Bb, input_l, out, n, q0);
      }
    }
  }
}

// Round 11
// 526.399 us; speedup vs baseline: 1.4981x; 1.0003x over previous
//
#include <hip/hip_runtime.h>
#include <hip/hip_bf16.h>
#include <cstdint>
#include <cstddef>

typedef __hip_bfloat16 bf16;
using short8 = __attribute__((ext_vector_type(8))) short;
using f32x4  = __attribute__((ext_vector_type(4))) float;
using float4v = __attribute__((ext_vector_type(4))) float;
using uint4v  = __attribute__((ext_vector_type(4))) unsigned int;

__device__ __forceinline__ float s2f(short s) {
  unsigned u = ((unsigned)(unsigned short)s) << 16;
  return __builtin_bit_cast(float, u);
}
__device__ __forceinline__ short f2s(float f) {  // RNE f32->bf16
  unsigned u = __builtin_bit_cast(unsigned, f);
  u += 0x7fffu + ((u >> 16) & 1u);
  return (short)(u >> 16);
}
__device__ __forceinline__ float bclo(unsigned u) { return __builtin_bit_cast(float, u << 16); }
__device__ __forceinline__ float bchi(unsigned u) { return __builtin_bit_cast(float, u & 0xFFFF0000u); }
__device__ __forceinline__ short bfbits(float f) {
  return __builtin_bit_cast(short, __float2bfloat16(f));
}

// ---------------- merged 1x1 conv + PReLU into zero-padded (+1 ring) f32 outputs ----
__global__ __launch_bounds__(256) void k_conv_all(
    const float* __restrict__ in_l, const float* __restrict__ in_s,
    const float* __restrict__ w_mlb, const float* __restrict__ b_mlb, const float* __restrict__ a_mlb,
    const float* __restrict__ w_m,   const float* __restrict__ b_m,   const float* __restrict__ a_m,
    const float* __restrict__ w_asm, const float* __restrict__ b_asm, const float* __restrict__ a_asm,
    float* __restrict__ MBpad, float* __restrict__ REFpad, float* __restrict__ BASEpad,
    int t1, int t2, int t3)
{
  int idx = blockIdx.x * 256 + threadIdx.x;
  const float *in, *w, *bi, *ap; float* o; int Cout, Hin, Win;
  if (idx < t1) { in = in_l; w = w_mlb; bi = b_mlb; ap = a_mlb; o = MBpad; Cout = 32; Hin = 96; Win = 96; }
  else if (idx < t1 + t2) { idx -= t1; in = in_s; w = w_m; bi = b_m; ap = a_m; o = REFpad; Cout = 32; Hin = 48; Win = 48; }
  else if (idx < t1 + t2 + t3) { idx -= t1 + t2; in = in_s; w = w_asm; bi = b_asm; ap = a_asm; o = BASEpad; Cout = 64; Hin = 48; Win = 48; }
  else return;
  int Wp = Win + 2, Hp = Hin + 2;
  int x = idx % Wp;
  int t = idx / Wp;
  int y = t % Hp; t /= Hp;
  int oc = t % Cout; int n = t / Cout;
  if (x == 0 || x == Wp - 1 || y == 0 || y == Hp - 1) { o[idx] = 0.0f; return; }
  int cs = Hin * Win;
  const float* ip = in + (size_t)n * 64 * cs + (size_t)(y - 1) * Win + (x - 1);
  const float* wp = w + oc * 64;
  float s = bi[oc];
#pragma unroll 16
  for (int ci = 0; ci < 64; ci++)
    s += wp[ci] * ip[(size_t)ci * cs];
  float a = ap[0];
  o[idx] = s >= 0.0f ? s : a * s;
}

// ---------------- residual pre-fill: out = input_l (PV partials atomicAdd on top) --
__global__ __launch_bounds__(256) void k_resid(
    const float* __restrict__ inl, float* __restrict__ out, int total4)
{
  int i = blockIdx.x * 256 + threadIdx.x;
  if (i < total4)
    ((float4v*)out)[i] = ((const float4v*)inl)[i];
}

// ---------------- merged gather/pack: Kp (stride 320) + Xp (stride 320) + Bb --------
// Xp and Bb sections vectorized x8 (bf16 short8 stores; 8 | 48 and 288 = 36*8 so
// groups never straddle validity/row boundaries). Same __float2bfloat16 per element
// -> bit-identical to the scalar version.
__global__ __launch_bounds__(256) void k_gather_all(
    const float* __restrict__ mbpad, const float* __restrict__ refpad,
    const float* __restrict__ basepad,
    bf16* __restrict__ Kp, bf16* __restrict__ Xp, bf16* __restrict__ Bb)
{
  int b = blockIdx.x;
  int tid = threadIdx.x;
  if (b < 2304) {
    // key patches, L2-normalized, scale 10 folded; one wave per (n,l); stride 320
    int wid = b * 4 + (tid >> 6);
    int lane = tid & 63;
    int n = wid / 2304, l = wid % 2304, lh = l / 48, lw = l % 48;
    float v[5]; float ss = 0.f;
#pragma unroll
    for (int i = 0; i < 5; i++) {
      int k = lane + 64 * i; v[i] = 0.f;
      if (k < 288) {
        int c = k / 9, rr = (k % 9) / 3, sc = k % 3;
        v[i] = refpad[((size_t)(n * 32 + c) * 50 + lh + rr) * 50 + lw + sc];
        ss += v[i] * v[i];
      }
    }
#pragma unroll
    for (int off = 32; off; off >>= 1) ss += __shfl_xor(ss, off);
    float inv = 10.f / (sqrtf(ss) + 1e-4f);
#pragma unroll
    for (int i = 0; i < 5; i++) {
      int k = lane + 64 * i;
      Kp[(size_t)wid * 320 + k] = __float2bfloat16(k < 288 ? v[i] * inv : 0.f);
    }
  } else if (b < 2304 + 5760) {
    // query patches Xp[n][p][320], 8 bf16 per thread
    int idx = (b - 2304) * 256 + tid;        // (n,p,g) with g fastest
    int g = idx % 40;                         // 40 groups of 8 per 320-row
    int p = (idx / 40) % 9216;
    int n = idx / (40 * 9216);
    short8 v8 = (short8){0, 0, 0, 0, 0, 0, 0, 0};
    if (g < 36) {
      int ph = p / 96, pw = p % 96;
#pragma unroll
      for (int j = 0; j < 8; j++) {
        int k = g * 8 + j;
        int c = k / 9, rr = (k % 9) / 3, sc = k % 3;
        v8[j] = bfbits(mbpad[((size_t)(n * 32 + c) * 98 + ph + rr) * 98 + pw + sc]);
      }
    }
    *(short8*)((short*)Xp + (size_t)idx * 8) = v8;
  } else {
    // base value matrix Bb[n][o][l], 8 bf16 per thread (row-contiguous reads)
    int idx = (b - 2304 - 5760) * 256 + tid;  // (n,o,l8) with l8 fastest
    int l8 = idx % 288;
    int o = (idx / 288) % 64;
    int n = idx / (288 * 64);
    int l0 = l8 * 8;
    int lh = l0 / 48, lw = l0 % 48;
    const float* src = &basepad[((size_t)(n * 64 + o) * 50 + lh + 1) * 50 + lw + 1];
    short8 v8;
#pragma unroll
    for (int j = 0; j < 8; j++) v8[j] = bfbits(src[j]);
    *(short8*)((short*)Bb + (size_t)idx * 8) = v8;
  }
}

// ---------------- stage 1: QK tile GEMM + chunk-local softmax, writes P~ ------------
// block: 64q x 256l, 2x2 waves of 32q x 128l. 64-wide k-stages.
// Staging schedule: pf(s+1) K prefetch is issued right after barrier B (full
// compute(s) of cover before its drain at next barrier A). X fragments for stage
// s+1 are loaded AFTER compute(s), overwriting xa in place (xa is dead there; no
// second buffer, no conditional copies -> no spill) — they drain at barrier A with
// two barriers + ds_write of latency cover, instead of stalling the first MFMA.
// blockIdx.z = sample-within-batch (z=0 in fallback mode -> offsets vanish).
__global__ __launch_bounds__(256, 3) void k_qk(
    const bf16* __restrict__ Xp, const bf16* __restrict__ Kp,
    bf16* __restrict__ attnT, float* __restrict__ statsM, float* __restrict__ statsZ,
    int nbase, int qlo)
{
  __shared__ __align__(16) short KsPs[256 * 72];   // union: Ks 256x(64+8) / Ps 64x264
  __shared__ float Sm[2][2][32];
  __shared__ float Sz[2][2][32];
  int z = blockIdx.z;
  int n = nbase + z;
  attnT += (size_t)z * 9216 * 2304;      // batched mode: full-size per-sample rows
  statsM += (size_t)z * 9 * 9216;
  statsZ += (size_t)z * 9 * 9216;
  int tid = threadIdx.x, lane = tid & 63, wv = tid >> 6;
  int quad = lane >> 4, m16 = lane & 15;
  int wr = wv >> 1, wc = wv & 1;
  int q0 = qlo + blockIdx.x * 64;
  int l0 = blockIdx.y * 256;

  f32x4 acc[2][8];
#pragma unroll
  for (int mi = 0; mi < 2; mi++)
#pragma unroll
    for (int t = 0; t < 8; t++) acc[mi][t] = (f32x4){0.f, 0.f, 0.f, 0.f};

  const short* Xrow = (const short*)Xp + ((size_t)n * 9216 + q0 + wr * 32 + m16) * 320;
  const short* Ksrc = (const short*)Kp + ((size_t)n * 2304 + l0) * 320;
  int srow = tid >> 2;            // 0..63 (rows srow + 64p)
  int scol = (tid & 3) * 16;      // 0,16,32,48

  // prologue: stage-0 K loads, then stage-0 X fragments
  short8 pf[8];
#pragma unroll
  for (int p = 0; p < 4; p++)
#pragma unroll
    for (int v = 0; v < 2; v++)
      pf[p * 2 + v] = *(const short8*)&Ksrc[(size_t)(srow + 64 * p) * 320 + scol + v * 8];
  short8 xa0 = *(const short8*)&Xrow[quad * 8];
  short8 xa1 = *(const short8*)&Xrow[16 * 320 + quad * 8];
  short8 xa2 = *(const short8*)&Xrow[32 + quad * 8];
  short8 xa3 = *(const short8*)&Xrow[16 * 320 + 32 + quad * 8];

#pragma unroll
  for (int s = 0; s < 5; s++) {
    if (s) __syncthreads();       // (A) read->write hazard; drains pf(s)+xa(s),
                                  //     both issued during stage s-1
#pragma unroll
    for (int p = 0; p < 4; p++)
#pragma unroll
      for (int v = 0; v < 2; v++)
        *(short8*)&KsPs[(srow + 64 * p) * 72 + scol + v * 8] = pf[p * 2 + v];
    __syncthreads();              // (B) write->read hazard
    if (s < 4) {
      int kn = (s + 1) * 64;
#pragma unroll
      for (int p = 0; p < 4; p++)
#pragma unroll
        for (int v = 0; v < 2; v++)
          pf[p * 2 + v] = *(const short8*)&Ksrc[(size_t)(srow + 64 * p) * 320 + kn + scol + v * 8];
    }
#pragma unroll
    for (int half = 0; half < 2; half++) {
      int kc = s * 64 + half * 32;
      if (kc >= 288) break;       // K=288; skip zero tail
      short8 a0 = half ? xa2 : xa0;
      short8 a1 = half ? xa3 : xa1;
#pragma unroll
      for (int t = 0; t < 8; t++) {
        short8 bfr = *(const short8*)&KsPs[(wc * 128 + t * 16 + m16) * 72 + half * 32 + quad * 8];
        acc[0][t] = __builtin_amdgcn_mfma_f32_16x16x32_bf16(a0, bfr, acc[0][t], 0, 0, 0);
        acc[1][t] = __builtin_amdgcn_mfma_f32_16x16x32_bf16(a1, bfr, acc[1][t], 0, 0, 0);
      }
    }
    if (s < 4) {                  // X fragments for stage s+1 (xa dead here)
      int kn = (s + 1) * 64;
      xa0 = *(const short8*)&Xrow[kn + quad * 8];
      xa1 = *(const short8*)&Xrow[16 * 320 + kn + quad * 8];
      xa2 = *(const short8*)&Xrow[kn + 32 + quad * 8];
      xa3 = *(const short8*)&Xrow[16 * 320 + kn + 32 + quad * 8];
    }
  }

  // local stats over this wave's 128 l
  float mloc[2][4], zloc[2][4], scale[2][4];
#pragma unroll
  for (int mi = 0; mi < 2; mi++)
#pragma unroll
    for (int r = 0; r < 4; r++) mloc[mi][r] = -3.0e38f;
#pragma unroll
  for (int mi = 0; mi < 2; mi++)
#pragma unroll
    for (int t = 0; t < 8; t++)
#pragma unroll
      for (int r = 0; r < 4; r++) mloc[mi][r] = fmaxf(mloc[mi][r], acc[mi][t][r]);
#pragma unroll
  for (int off = 1; off < 16; off <<= 1)
#pragma unroll
    for (int mi = 0; mi < 2; mi++)
#pragma unroll
      for (int r = 0; r < 4; r++) mloc[mi][r] = fmaxf(mloc[mi][r], __shfl_xor(mloc[mi][r], off));
#pragma unroll
  for (int mi = 0; mi < 2; mi++)
#pragma unroll
    for (int r = 0; r < 4; r++) zloc[mi][r] = 0.f;
#pragma unroll
  for (int mi = 0; mi < 2; mi++)
#pragma unroll
    for (int t = 0; t < 8; t++)
#pragma unroll
      for (int r = 0; r < 4; r++) {
        float e = __expf(acc[mi][t][r] - mloc[mi][r]);
        acc[mi][t][r] = e;
        zloc[mi][r] += e;
      }
#pragma unroll
  for (int off = 1; off < 16; off <<= 1)
#pragma unroll
    for (int mi = 0; mi < 2; mi++)
#pragma unroll
      for (int r = 0; r < 4; r++) zloc[mi][r] += __shfl_xor(zloc[mi][r], off);
  if (m16 == 0) {
#pragma unroll
    for (int mi = 0; mi < 2; mi++)
#pragma unroll
      for (int r = 0; r < 4; r++) {
        int qi = mi * 16 + quad * 4 + r;
        Sm[wc][wr][qi] = mloc[mi][r];
        Sz[wc][wr][qi] = zloc[mi][r];
      }
  }
  __syncthreads();   // stats visible; also guards Ks reuse as Ps below
#pragma unroll
  for (int mi = 0; mi < 2; mi++)
#pragma unroll
    for (int r = 0; r < 4; r++) {
      int qi = mi * 16 + quad * 4 + r;
      float mo = Sm[wc ^ 1][wr][qi];
      float zo = Sz[wc ^ 1][wr][qi];
      float mc = fmaxf(mloc[mi][r], mo);
      float sc = __expf(mloc[mi][r] - mc);
      scale[mi][r] = sc;
      if (m16 == 0 && wc == 0) {
        float zc = zloc[mi][r] * sc + zo * __expf(mo - mc);
        int qq = q0 + wr * 32 + qi;
        statsM[blockIdx.y * 9216 + qq] = mc;
        statsZ[blockIdx.y * 9216 + qq] = zc;
      }
    }
  // write P~ tile through LDS (coalesced global stores)
#pragma unroll
  for (int mi = 0; mi < 2; mi++)
#pragma unroll
    for (int t = 0; t < 8; t++)
#pragma unroll
      for (int r = 0; r < 4; r++)
        KsPs[(wr * 32 + mi * 16 + quad * 4 + r) * 264 + wc * 128 + t * 16 + m16] =
            f2s(acc[mi][t][r] * scale[mi][r]);
  __syncthreads();
  {
    int row = tid >> 2, part = tid & 3;
    short* dst = (short*)attnT + (size_t)(q0 - qlo + row) * 2304 + l0 + part * 64;
    const short* sp = &KsPs[row * 264 + part * 64];
#pragma unroll
    for (int v = 0; v < 8; v++)
      *(short8*)&dst[v * 8] = *(const short8*)&sp[v * 8];
  }
}

// ---------------- stage 2: combine chunk stats -> alpha[c][q] ----------------
// blockIdx.y = sample-within-batch.
__global__ __launch_bounds__(256) void k_alpha(
    const float* __restrict__ statsM, const float* __restrict__ statsZ,
    float* __restrict__ alpha, int qlo, int qlen)
{
  int z = blockIdx.y;
  statsM += (size_t)z * 9 * 9216;
  statsZ += (size_t)z * 9 * 9216;
  alpha  += (size_t)z * 9 * 9216;
  int i = blockIdx.x * 256 + threadIdx.x;
  if (i >= qlen) return;
  int q = qlo + i;
  float M = -3.0e38f;
#pragma unroll
  for (int c = 0; c < 9; c++) M = fmaxf(M, statsM[c * 9216 + q]);
  float Z = 0.f;
#pragma unroll
  for (int c = 0; c < 9; c++) Z += statsZ[c * 9216 + q] * __expf(statsM[c * 9216 + q] - M);
  float invZ = 1.f / Z;
#pragma unroll
  for (int c = 0; c < 9; c++) alpha[c * 9216 + q] = __expf(statsM[c * 9216 + q] - M) * invZ;
}

// ---- stage 3: 9-point diagonal stencil with fused alpha, 16 l per thread ----------
// A2[l,q] = sum_d P~[l+dl, q+dq] * alpha[c(l+dl)][q+dq]
// aligned uint4 loads + funnel shifts; XCD-swizzled contiguous q bands.
// blockIdx.z = sample-within-batch.
__global__ __launch_bounds__(256) void k_a2(
    const bf16* __restrict__ attnT, const float* __restrict__ alpha,
    bf16* __restrict__ A2, int q0, int qlo)
{
  int z = blockIdx.z;
  attnT += (size_t)z * 9216 * 2304;
  alpha += (size_t)z * 9 * 9216;
  A2    += (size_t)z * 9216 * 2304;
  int bpx = gridDim.x >> 3;
  int nb = (blockIdx.x & 7) * bpx + (blockIdx.x >> 3);
  int g = nb * 256 + threadIdx.x;
  int qrel = g / 144;                 // 144 groups of 16 per q row
  int j = g - qrel * 144;
  int l0 = j * 16;
  int q = q0 + qrel;
  int h = q / 96, w = q - h * 96;
  int lh = l0 / 48, lw0 = l0 - lh * 48;   // 0,16,32 (16 | 48: never crosses lh rows)
  const short* att = (const short*)attnT;
  float acc[16];
#pragma unroll
  for (int k = 0; k < 16; k++) acc[k] = 0.f;
#pragma unroll
  for (int di = -1; di <= 1; di++) {
    int hh = h + di, lhh = lh + di;
    if (hh < 0 || hh >= 96 || lhh < 0 || lhh >= 48) continue;
    int lb = l0 + 48 * di;            // multiple of 16 -> 32B aligned
    int qv = q + 96 * di;
    const short* r0 = att + (size_t)(qv - qlo) * 2304;
    int c0 = lb >> 8;                 // 16-span never crosses a 256-chunk
    const float* alc = alpha + c0 * 9216;
    { // dj = 0
      float a = alc[qv];
      uint4v Va = *(const uint4v*)(r0 + lb);
      uint4v Vb = *(const uint4v*)(r0 + lb + 8);
#pragma unroll
      for (int k = 0; k < 4; k++) {
        acc[2 * k]      += bclo(Va[k]) * a;  acc[2 * k + 1]  += bchi(Va[k]) * a;
        acc[8 + 2 * k]  += bclo(Vb[k]) * a;  acc[9 + 2 * k]  += bchi(Vb[k]) * a;
      }
    }
    if (w > 0) { // dj = -1: shorts [lb-1 .. lb+14]; elem0 may be chunk c0-1
      const short* rm = r0 - 2304;
      int qp = qv - 1;
      float am = alc[qp];
      float a0 = ((lb & 255) == 0 && c0 > 0) ? alpha[(c0 - 1) * 9216 + qp] : am;
      uint4v Ma = *(const uint4v*)(rm + lb);
      uint4v Mb = *(const uint4v*)(rm + lb + 8);
      unsigned P = *(const unsigned*)(rm + lb - 2);
      unsigned D[8] = { Ma[0], Ma[1], Ma[2], Ma[3], Mb[0], Mb[1], Mb[2], Mb[3] };
      unsigned E0 = (P >> 16) | (D[0] << 16);
      if (lw0 == 0) E0 &= 0xFFFF0000u;     // elem0 would wrap to prev lh row
      acc[0] += bclo(E0) * a0;  acc[1] += bchi(E0) * am;
#pragma unroll
      for (int k = 1; k < 8; k++) {
        unsigned Ek = (D[k - 1] >> 16) | (D[k] << 16);
        acc[2 * k] += bclo(Ek) * am;  acc[2 * k + 1] += bchi(Ek) * am;
      }
    }
    if (w < 95) { // dj = +1: shorts [lb+1 .. lb+16]; elem15 may be chunk c0+1
      const short* rp = r0 + 2304;
      int qp = qv + 1;
      float am = alc[qp];
      float a15 = ((lb & 255) == 240 && c0 < 8) ? alpha[(c0 + 1) * 9216 + qp] : am;
      uint4v Pa = *(const uint4v*)(rp + lb);
      uint4v Pb = *(const uint4v*)(rp + lb + 8);
      unsigned N = *(const unsigned*)(rp + lb + 16);
      unsigned D[9] = { Pa[0], Pa[1], Pa[2], Pa[3], Pb[0], Pb[1], Pb[2], Pb[3], N };
      unsigned F7 = (D[7] >> 16) | (D[8] << 16);
      if (lw0 == 32) F7 &= 0x0000FFFFu;    // elem15 would wrap to next lh row
#pragma unroll
      for (int k = 0; k < 7; k++) {
        unsigned Fk = (D[k] >> 16) | (D[k + 1] << 16);
        acc[2 * k] += bclo(Fk) * am;  acc[2 * k + 1] += bchi(Fk) * am;
      }
      acc[14] += bclo(F7) * am;  acc[15] += bchi(F7) * a15;
    }
  }
  short8 o0, o1;
#pragma unroll
  for (int k = 0; k < 8; k++) { o0[k] = f2s(acc[k]); o1[k] = f2s(acc[8 + k]); }
  short* dst = (short*)A2 + (size_t)qrel * 2304 + l0;
  *(short8*)dst = o0;
  *(short8*)(dst + 8) = o1;
}

// ---- stage 4: PV GEMM, split-K x2 across blocks + in-block split-K ----------------
// block = 16q x 64o; blockIdx.y = k-half; 4 waves each own 288 of the half's 1152
// (no barriers in k-loop), LDS reduction, atomicAdd(out, 0.25*partial) epilogue
// (out pre-filled with residual by k_resid). blockIdx.z = sample-within-batch.
__global__ __launch_bounds__(256) void k_pv3(
    const bf16* __restrict__ A2, const bf16* __restrict__ Bb,
    float* __restrict__ out, int nbase, int q0base)
{
  __shared__ float Cred[4][16][67];
  int z = blockIdx.z;
  int n = nbase + z;
  A2 += (size_t)z * 9216 * 2304;
  int tid = threadIdx.x, lane = tid & 63, wv = tid >> 6;
  int quad = lane >> 4, m16 = lane & 15;
  int qb = blockIdx.x * 16;
  int kbase = blockIdx.y * 1152 + wv * 288;
  f32x4 acc[4];
#pragma unroll
  for (int t = 0; t < 4; t++) acc[t] = (f32x4){0.f, 0.f, 0.f, 0.f};

  const short* Ap = (const short*)A2 + (size_t)qb * 2304 + kbase;
  const short* Bp = (const short*)Bb + (size_t)n * 64 * 2304 + kbase;

#pragma unroll
  for (int it = 0; it < 9; it++) {
    int kw = it * 32;
    short8 a = *(const short8*)&Ap[(size_t)m16 * 2304 + kw + quad * 8];
#pragma unroll
    for (int ni = 0; ni < 4; ni++) {
      short8 b = *(const short8*)&Bp[(size_t)(ni * 16 + m16) * 2304 + kw + quad * 8];
      acc[ni] = __builtin_amdgcn_mfma_f32_16x16x32_bf16(a, b, acc[ni], 0, 0, 0);
    }
  }
#pragma unroll
  for (int ni = 0; ni < 4; ni++)
#pragma unroll
    for (int r = 0; r < 4; r++)
      Cred[wv][quad * 4 + r][ni * 16 + m16] = acc[ni][r];
  __syncthreads();
  {
    int o = tid >> 2;                // 0..63
    int qg = (tid & 3) * 4;          // 0..12
    size_t oid = ((size_t)(n * 64 + o)) * 9216 + q0base + qb + qg;
#pragma unroll
    for (int j = 0; j < 4; j++) {
      float s = Cred[0][qg + j][o] + Cred[1][qg + j][o] + Cred[2][qg + j][o] + Cred[3][qg + j][o];
      atomicAdd(&out[oid + j], 0.25f * s);
    }
  }
}

extern "C" void kernel_launch(void* const* d_in, const int* in_sizes, int n_in,
                              void* d_out, int out_size, void* d_ws, size_t ws_size,
                              hipStream_t stream)
{
  (void)in_sizes; (void)n_in; (void)out_size;
  const float* input_l = (const float*)d_in[0];
  const float* input_s = (const float*)d_in[1];
  const float* w_mlb = (const float*)d_in[2];
  const float* b_mlb = (const float*)d_in[3];
  const float* a_mlb = (const float*)d_in[4];
  const float* w_m   = (const float*)d_in[5];
  const float* b_m   = (const float*)d_in[6];
  const float* a_m   = (const float*)d_in[7];
  const float* w_asm = (const float*)d_in[8];
  const float* b_asm = (const float*)d_in[9];
  const float* a_asm = (const float*)d_in[10];
  float* out = (float*)d_out;

  char* base = (char*)d_ws;
  size_t off = 0;
  auto carve = [&](size_t bytes) -> char* {
    char* r = base + off;
    off += (bytes + 255) & ~(size_t)255;
    return r;
  };

  float* MBpad   = (float*)carve((size_t)4 * 32 * 98 * 98 * 4);
  float* REFpad  = (float*)carve((size_t)4 * 32 * 50 * 50 * 4);
  float* BASEpad = (float*)carve((size_t)4 * 64 * 50 * 50 * 4);
  bf16*  Kp      = (bf16*)carve((size_t)4 * 2304 * 320 * 2);
  bf16*  Xp      = (bf16*)carve((size_t)4 * 9216 * 320 * 2);
  bf16*  Bb      = (bf16*)carve((size_t)4 * 64 * 2304 * 2);
  float* statsM  = (float*)carve((size_t)2 * 9 * 9216 * 4);   // x2 for paired batch
  float* statsZ  = (float*)carve((size_t)2 * 9 * 9216 * 4);
  float* alpha   = (float*)carve((size_t)2 * 9 * 9216 * 4);
  size_t fixedOff = off;

  auto need = [&](int qmax, int psplit, int B) -> size_t {
    size_t a = (((size_t)qmax * 2304 * 2) * B + 255) & ~(size_t)255;
    size_t b2 = (((size_t)psplit * 2304 * 2) * B + 255) & ~(size_t)255;
    return fixedOff + a + b2;
  };
  int nsplit, qmax, psplit, batchB;
  if (need(9216, 9216, 2) <= ws_size)      { batchB = 2; nsplit = 1; qmax = 9216; psplit = 9216; }
  else if (need(9216, 9216, 1) <= ws_size) { batchB = 1; nsplit = 1; qmax = 9216; psplit = 9216; }
  else if (need(5120, 4608, 1) <= ws_size) { batchB = 1; nsplit = 2; qmax = 5120; psplit = 4608; }
  else                                     { batchB = 1; nsplit = 4; qmax = 2816; psplit = 2304; }

  bf16* attnT = (bf16*)carve((size_t)qmax * 2304 * 2 * batchB);
  bf16* A2    = (bf16*)carve((size_t)psplit * 2304 * 2 * batchB);

  // ---- prep (all samples, 3 dispatches) ----
  {
    int t1 = 4 * 32 * 98 * 98;
    int t2 = 4 * 32 * 50 * 50;
    int t3 = 4 * 64 * 50 * 50;
    int tt = t1 + t2 + t3;
    k_conv_all<<<dim3((tt + 255) / 256), dim3(256), 0, stream>>>(
        input_l, input_s, w_mlb, b_mlb, a_mlb, w_m, b_m, a_m, w_asm, b_asm, a_asm,
        MBpad, REFpad, BASEpad, t1, t2, t3);
    k_resid<<<dim3(2304), dim3(256), 0, stream>>>(input_l, out, 4 * 64 * 9216 / 4);
    k_gather_all<<<dim3(2304 + 5760 + 288), dim3(256), 0, stream>>>(
        MBpad, REFpad, BASEpad, Kp, Xp, Bb);
  }

  if (batchB == 2) {
    // ---- paired-sample batching: 8 attention dispatches total ----
    for (int p = 0; p < 2; p++) {
      int nb = p * 2;
      k_qk<<<dim3(144, 9, 2), dim3(256), 0, stream>>>(Xp, Kp, attnT, statsM, statsZ, nb, 0);
      k_alpha<<<dim3(36, 2), dim3(256), 0, stream>>>(statsM, statsZ, alpha, 0, 9216);
      k_a2<<<dim3(5184, 1, 2), dim3(256), 0, stream>>>(attnT, alpha, A2, 0, 0);
      k_pv3<<<dim3(576, 2, 2), dim3(256), 0, stream>>>(A2, Bb, out, nb, 0);
    }
  } else {
    // ---- fallback: per (sample, query band), z = 0 everywhere ----
    for (int n = 0; n < 4; n++) {
      for (int s = 0; s < nsplit; s++) {
        int q0 = s * psplit;
        int qlo = q0 - 256; if (qlo < 0) qlo = 0;
        int qhi = q0 + psplit + 256; if (qhi > 9216) qhi = 9216;
        int qlen = qhi - qlo;  // multiple of 256 by construction
        k_qk<<<dim3(qlen / 64, 9, 1), dim3(256), 0, stream>>>(Xp, Kp, attnT, statsM, statsZ, n, qlo);
        k_alpha<<<dim3(qlen / 256, 1), dim3(256), 0, stream>>>(statsM, statsZ, alpha, qlo, qlen);
        k_a2<<<dim3(psplit * 144 / 256, 1, 1), dim3(256), 0, stream>>>(attnT, alpha, A2, q0, qlo);
        k_pv3<<<dim3(psplit / 16, 2, 1), dim3(256), 0, stream>>>(A2, Bb, out, n, q0);
      }
    }
  }
}